// Round 1
// baseline (2855.794 us; speedup 1.0000x reference)
//
#include <hip/hip_runtime.h>
#include <stdint.h>

#define B    512
#define N    50257
#define BLK  512
#define NWAVE (BLK / 64)
#define THRESH 0.4f

// Weights are softmax outputs: all strictly positive floats.
// For positive floats, the raw bit pattern is monotonically increasing with
// value. Complementing gives a key whose ASCENDING stable order == DESCENDING
// weight order with ties broken by ascending original index (stable LSD radix
// preserves input order), matching jnp.argsort(-weights) (stable).
__device__ __forceinline__ uint32_t sort_key(float w) {
    return ~__float_as_uint(w);
}

template <int SHIFT>
__global__ __launch_bounds__(BLK) void radix_pass(const float* __restrict__ wts,
                                                  const uint32_t* __restrict__ src,
                                                  uint32_t* __restrict__ dst) {
    __shared__ uint32_t hist[256];
    __shared__ uint32_t scanb[256];
    __shared__ uint32_t running[256];
    __shared__ uint32_t waveCnt[NWAVE][256];

    const int row = blockIdx.x;
    const size_t base = (size_t)row * N;
    const int tid  = threadIdx.x;
    const int lane = tid & 63;
    const int wv   = tid >> 6;

    // ---- Phase A: per-row digit histogram ----
    if (tid < 256) hist[tid] = 0;
    __syncthreads();
    for (int i = tid; i < N; i += BLK) {
        uint32_t idx = (SHIFT == 0) ? (uint32_t)i : src[base + i];
        uint32_t d = (sort_key(wts[base + idx]) >> SHIFT) & 255u;
        atomicAdd(&hist[d], 1u);
    }
    __syncthreads();

    // ---- Phase B: exclusive scan of 256 digit counts ----
    if (tid < 256) scanb[tid] = hist[tid];
    __syncthreads();
    for (int off = 1; off < 256; off <<= 1) {
        uint32_t add = 0;
        if (tid < 256 && tid >= off) add = scanb[tid - off];
        __syncthreads();
        if (tid < 256) scanb[tid] += add;
        __syncthreads();
    }
    if (tid < 256) running[tid] = (tid == 0) ? 0u : scanb[tid - 1];
    __syncthreads();

    // ---- Phase C: stable scatter, tiles in index order ----
    const int numTiles = (N + BLK - 1) / BLK;
    for (int t = 0; t < numTiles; ++t) {
        // zero per-wave counters
        for (int j = tid; j < NWAVE * 256; j += BLK) ((uint32_t*)waveCnt)[j] = 0;
        __syncthreads();

        const int i = t * BLK + tid;
        const bool valid = (i < N);
        uint32_t idx = 0, d = 0;
        if (valid) {
            idx = (SHIFT == 0) ? (uint32_t)i : src[base + i];
            d = (sort_key(wts[base + idx]) >> SHIFT) & 255u;
        }
        // wave-level same-digit matching (8 ballots)
        unsigned long long active = __ballot(valid);
        unsigned long long peers = active;
        #pragma unroll
        for (int b = 0; b < 8; ++b) {
            unsigned long long bit = __ballot(valid && ((d >> b) & 1u));
            peers &= ((d >> b) & 1u) ? bit : ~bit;
        }
        const unsigned long long lower = peers & ((1ull << lane) - 1ull);
        const uint32_t rank = (uint32_t)__popcll(lower);
        if (valid && lower == 0ull) waveCnt[wv][d] = (uint32_t)__popcll(peers);
        __syncthreads();

        // per-digit: exclusive prefix over waves + running bucket offset
        if (tid < 256) {
            uint32_t s = running[tid];
            #pragma unroll
            for (int w = 0; w < NWAVE; ++w) {
                uint32_t c = waveCnt[w][tid];
                waveCnt[w][tid] = s;
                s += c;
            }
            running[tid] = s;
        }
        __syncthreads();

        if (valid) {
            uint32_t pos = waveCnt[wv][d] + rank;
            dst[base + pos] = idx;
        }
        __syncthreads();
    }
}

__global__ __launch_bounds__(BLK) void finalize(const float* __restrict__ wts,
                                                const uint32_t* __restrict__ sidx,
                                                float* __restrict__ out0,
                                                float* __restrict__ out1,
                                                float* __restrict__ out2) {
    __shared__ float waveSum[NWAVE];
    __shared__ int   waveFirst[NWAVE];
    __shared__ float waveCum[NWAVE];
    __shared__ int   s_k;
    __shared__ float s_total;

    const int row = blockIdx.x;
    const size_t base = (size_t)row * N;
    const int tid  = threadIdx.x;
    const int lane = tid & 63;
    const int wv   = tid >> 6;

    if (tid == 0) { s_k = -1; s_total = 0.f; }
    __syncthreads();

    float carry = 0.f;
    const int numTiles = (N + BLK - 1) / BLK;
    for (int t = 0; t < numTiles; ++t) {
        const int i = t * BLK + tid;
        const bool valid = (i < N);
        float w = valid ? wts[base + sidx[base + i]] : 0.f;

        // wave inclusive scan
        float s = w;
        #pragma unroll
        for (int o = 1; o < 64; o <<= 1) {
            float u = __shfl_up(s, o);
            if (lane >= o) s += u;
        }
        if (lane == 63) waveSum[wv] = s;
        __syncthreads();

        float prefix = 0.f, blockTot = 0.f;
        #pragma unroll
        for (int w2 = 0; w2 < NWAVE; ++w2) {
            float t2 = waveSum[w2];
            if (w2 < wv) prefix += t2;
            blockTot += t2;
        }
        const float cum = carry + prefix + s;   // inclusive cumsum at position i

        const bool exceed = valid && (cum > THRESH);
        const unsigned long long bal = __ballot(exceed);
        const int fl = (bal == 0ull) ? 64 : (__ffsll(bal) - 1);
        if (lane == 0) waveFirst[wv] = fl;
        if (fl < 64 && lane == fl) waveCum[wv] = cum;
        __syncthreads();
        if (tid == 0) {
            for (int w2 = 0; w2 < NWAVE; ++w2) {
                if (waveFirst[w2] < 64) {
                    s_k = t * BLK + w2 * 64 + waveFirst[w2] + 1;
                    s_total = waveCum[w2];
                    break;
                }
            }
        }
        __syncthreads();
        if (s_k >= 0) break;          // uniform (read from LDS after barrier)
        carry += blockTot;
        __syncthreads();              // protect waveSum/waveFirst reuse
    }

    int k = s_k;
    float total = s_total;
    if (k < 0) { k = N; total = carry; }

    // NOTE: sidx aliases out1's memory region. Per-thread read-before-write on
    // identical index i; each i is touched by exactly one thread. Safe.
    for (int i = tid; i < N; i += BLK) {
        const uint32_t idx = sidx[base + i];
        const float w = wts[base + idx];
        out0[base + i] = (float)idx;
        out1[base + i] = (i < k) ? (w / total) : 0.f;
    }
    if (tid == 0) out2[row] = (float)k;
}

extern "C" void kernel_launch(void* const* d_in, const int* in_sizes, int n_in,
                              void* d_out, int out_size, void* d_ws, size_t ws_size,
                              hipStream_t stream) {
    const float* wts = (const float*)d_in[0];
    float* out0 = (float*)d_out;                       // sorted_idx (as f32)
    float* out1 = out0 + (size_t)B * N;                // norm_w
    float* out2 = out0 + 2 * (size_t)B * N;            // k (as f32)

    // Ping-pong index buffers inside d_out's two B*N regions (no d_ws needed).
    uint32_t* bufA = (uint32_t*)out0;
    uint32_t* bufB = (uint32_t*)out1;

    dim3 g(B), b(BLK);
    radix_pass<0 ><<<g, b, 0, stream>>>(wts, nullptr, bufA);
    radix_pass<8 ><<<g, b, 0, stream>>>(wts, bufA, bufB);
    radix_pass<16><<<g, b, 0, stream>>>(wts, bufB, bufA);
    radix_pass<24><<<g, b, 0, stream>>>(wts, bufA, bufB);  // final idx in bufB
    finalize<<<g, b, 0, stream>>>(wts, bufB, out0, out1, out2);
}

// Round 2
// 1507.760 us; speedup vs baseline: 1.8941x; 1.8941x over previous
//
#include <hip/hip_runtime.h>
#include <stdint.h>

#define B    512
#define N    50257
#define BLK  512
#define NWAVE (BLK / 64)
#define THRESH 0.4f

// Softmax weights are strictly positive floats: raw bit pattern is monotone
// in value. Complement -> ascending stable order == descending weight order
// with ties broken by ascending original index (LSD radix is stable),
// matching jnp.argsort(-weights).
__device__ __forceinline__ uint32_t sort_key(float w) {
    return ~__float_as_uint(w);
}

// ---------------------------------------------------------------------------
// FAST PATH (requires d_ws >= WS_NEED): gather-free key+idx streaming sort.
// ---------------------------------------------------------------------------

struct KT { uint32_t k; float total; };

// ballot-aggregated histogram add (for skewed digits: one atomic per distinct
// digit per wave instead of per lane)
__device__ __forceinline__ void hist_add_matched(uint32_t* bins, uint32_t d, bool valid) {
    unsigned long long peers = __ballot(valid);
    #pragma unroll
    for (int b = 0; b < 8; ++b) {
        unsigned long long bit = __ballot(valid && ((d >> b) & 1u));
        peers &= ((d >> b) & 1u) ? bit : ~bit;
    }
    if (valid) {
        const int lane = threadIdx.x & 63;
        const unsigned long long lower = peers & ((1ull << lane) - 1ull);
        if (lower == 0ull) atomicAdd(&bins[d], (uint32_t)__popcll(peers));
    }
}

// One block per row: all 4 digit histograms in a single sequential read
// (digit histograms are independent of element order), then exclusive-scan
// each into bucket-start offsets.
__global__ __launch_bounds__(BLK) void hist4(const float* __restrict__ wts,
                                             uint32_t* __restrict__ histWS) {
    __shared__ uint32_t h[4][256];
    __shared__ uint32_t sc[256];
    const int row = blockIdx.x;
    const size_t base = (size_t)row * N;
    const int tid = threadIdx.x;

    for (int j = tid; j < 4 * 256; j += BLK) ((uint32_t*)h)[j] = 0;
    __syncthreads();

    const int iters = (N + BLK - 1) / BLK;
    for (int it = 0; it < iters; ++it) {
        const int i = it * BLK + tid;
        const bool valid = (i < N);
        const uint32_t key = valid ? sort_key(wts[base + i]) : 0u;
        if (valid) {
            atomicAdd(&h[0][key & 255u], 1u);          // mantissa bytes: ~uniform
            atomicAdd(&h[1][(key >> 8) & 255u], 1u);
        }
        hist_add_matched(h[2], (key >> 16) & 255u, valid);  // exponent-ish: skewed
        hist_add_matched(h[3], (key >> 24) & 255u, valid);
    }
    __syncthreads();

    for (int p = 0; p < 4; ++p) {
        if (tid < 256) sc[tid] = h[p][tid];
        __syncthreads();
        for (int off = 1; off < 256; off <<= 1) {
            uint32_t add = 0;
            if (tid < 256 && tid >= off) add = sc[tid - off];
            __syncthreads();
            if (tid < 256) sc[tid] += add;
            __syncthreads();
        }
        if (tid < 256)
            histWS[((size_t)row * 4 + p) * 256 + tid] = (tid == 0) ? 0u : sc[tid - 1];
        __syncthreads();
    }
}

// Stable LSD scatter pass carrying (key u32, idx u16). FIRST computes keys
// from the weights (identity idx); LAST emits sorted idx (u32) into out0's
// region and the sorted weight (recovered exactly from key) into out1.
template <int SHIFT, bool FIRST, bool LAST>
__global__ __launch_bounds__(BLK) void scatter_pass(const float* __restrict__ wts,
                                                    const uint32_t* __restrict__ keySrc,
                                                    const uint16_t* __restrict__ idxSrc,
                                                    uint32_t* __restrict__ keyDst,
                                                    uint16_t* __restrict__ idxDst,
                                                    uint32_t* __restrict__ outIdx,
                                                    float* __restrict__ outW,
                                                    const uint32_t* __restrict__ histWS) {
    __shared__ uint32_t running[256];
    __shared__ uint32_t waveCnt[NWAVE][256];

    const int row = blockIdx.x;
    const size_t base = (size_t)row * N;
    const int tid  = threadIdx.x;
    const int lane = tid & 63;
    const int wv   = tid >> 6;
    constexpr int PASS = SHIFT / 8;

    if (tid < 256) running[tid] = histWS[((size_t)row * 4 + PASS) * 256 + tid];
    __syncthreads();

    const int numTiles = (N + BLK - 1) / BLK;
    for (int t = 0; t < numTiles; ++t) {
        for (int j = tid; j < NWAVE * 256; j += BLK) ((uint32_t*)waveCnt)[j] = 0;
        __syncthreads();

        const int i = t * BLK + tid;
        const bool valid = (i < N);
        uint32_t key = 0, idx = 0, d = 0;
        if (valid) {
            if (FIRST) { key = sort_key(wts[base + i]); idx = (uint32_t)i; }
            else       { key = keySrc[base + i]; idx = (uint32_t)idxSrc[base + i]; }
            d = (key >> SHIFT) & 255u;
        }
        // wave-level same-digit matching (8 ballots) -> stable intra-wave rank
        unsigned long long peers = __ballot(valid);
        #pragma unroll
        for (int b = 0; b < 8; ++b) {
            unsigned long long bit = __ballot(valid && ((d >> b) & 1u));
            peers &= ((d >> b) & 1u) ? bit : ~bit;
        }
        const unsigned long long lower = peers & ((1ull << lane) - 1ull);
        const uint32_t rank = (uint32_t)__popcll(lower);
        if (valid && lower == 0ull) waveCnt[wv][d] = (uint32_t)__popcll(peers);
        __syncthreads();

        if (tid < 256) {
            uint32_t s = running[tid];
            #pragma unroll
            for (int w = 0; w < NWAVE; ++w) {
                uint32_t c = waveCnt[w][tid];
                waveCnt[w][tid] = s;
                s += c;
            }
            running[tid] = s;
        }
        __syncthreads();

        if (valid) {
            const uint32_t pos = waveCnt[wv][d] + rank;
            if (LAST) {
                outIdx[base + pos] = idx;
                outW[base + pos]   = __uint_as_float(~key);
            } else {
                keyDst[base + pos] = key;
                idxDst[base + pos] = (uint16_t)idx;
            }
        }
        __syncthreads();
    }
}

// Per-row sequential scan over the (already sorted) weights with early exit.
__global__ __launch_bounds__(BLK) void scan_k(const float* __restrict__ sortedW,
                                              KT* __restrict__ kt,
                                              float* __restrict__ out2) {
    __shared__ float waveSum[NWAVE];
    __shared__ int   waveFirst[NWAVE];
    __shared__ float waveCum[NWAVE];
    __shared__ int   s_k;
    __shared__ float s_total;

    const int row = blockIdx.x;
    const size_t base = (size_t)row * N;
    const int tid  = threadIdx.x;
    const int lane = tid & 63;
    const int wv   = tid >> 6;

    if (tid == 0) { s_k = -1; s_total = 0.f; }
    __syncthreads();

    float carry = 0.f;
    const int numTiles = (N + BLK - 1) / BLK;
    for (int t = 0; t < numTiles; ++t) {
        const int i = t * BLK + tid;
        const bool valid = (i < N);
        float w = valid ? sortedW[base + i] : 0.f;

        float s = w;
        #pragma unroll
        for (int o = 1; o < 64; o <<= 1) {
            float u = __shfl_up(s, o);
            if (lane >= o) s += u;
        }
        if (lane == 63) waveSum[wv] = s;
        __syncthreads();

        float prefix = 0.f, blockTot = 0.f;
        #pragma unroll
        for (int w2 = 0; w2 < NWAVE; ++w2) {
            float t2 = waveSum[w2];
            if (w2 < wv) prefix += t2;
            blockTot += t2;
        }
        const float cum = carry + prefix + s;

        const bool exceed = valid && (cum > THRESH);
        const unsigned long long bal = __ballot(exceed);
        const int fl = (bal == 0ull) ? 64 : (__ffsll(bal) - 1);
        if (lane == 0) waveFirst[wv] = fl;
        if (fl < 64 && lane == fl) waveCum[wv] = cum;
        __syncthreads();
        if (tid == 0) {
            for (int w2 = 0; w2 < NWAVE; ++w2) {
                if (waveFirst[w2] < 64) {
                    s_k = t * BLK + w2 * 64 + waveFirst[w2] + 1;
                    s_total = waveCum[w2];
                    break;
                }
            }
        }
        __syncthreads();
        if (s_k >= 0) break;
        carry += blockTot;
        __syncthreads();
    }

    if (tid == 0) {
        int k = s_k;
        float total = s_total;
        if (k < 0) { k = N; total = carry; }
        kt[row].k = (uint32_t)k;
        kt[row].total = total;
        out2[row] = (float)k;
    }
}

// Fully parallel elementwise finalize: idx u32 -> float in place, normalize w.
__global__ __launch_bounds__(BLK) void finalize_norm(const uint32_t* __restrict__ idxU,
                                                     float* __restrict__ out0,
                                                     float* __restrict__ out1,
                                                     const KT* __restrict__ kt) {
    const int row = blockIdx.y;
    const int i = blockIdx.x * BLK + threadIdx.x;
    if (i >= N) return;
    const size_t base = (size_t)row * N;
    const KT p = kt[row];
    const uint32_t idx = idxU[base + i];
    const float w = out1[base + i];
    out0[base + i] = (float)idx;
    out1[base + i] = ((uint32_t)i < p.k) ? (w / p.total) : 0.f;
}

// ---------------------------------------------------------------------------
// FALLBACK PATH (round-1, gather-based): used when d_ws is too small.
// ---------------------------------------------------------------------------

template <int SHIFT>
__global__ __launch_bounds__(BLK) void radix_pass_fb(const float* __restrict__ wts,
                                                     const uint32_t* __restrict__ src,
                                                     uint32_t* __restrict__ dst) {
    __shared__ uint32_t hist[256];
    __shared__ uint32_t scanb[256];
    __shared__ uint32_t running[256];
    __shared__ uint32_t waveCnt[NWAVE][256];

    const int row = blockIdx.x;
    const size_t base = (size_t)row * N;
    const int tid  = threadIdx.x;
    const int lane = tid & 63;
    const int wv   = tid >> 6;

    if (tid < 256) hist[tid] = 0;
    __syncthreads();
    for (int i = tid; i < N; i += BLK) {
        uint32_t idx = (SHIFT == 0) ? (uint32_t)i : src[base + i];
        uint32_t d = (sort_key(wts[base + idx]) >> SHIFT) & 255u;
        atomicAdd(&hist[d], 1u);
    }
    __syncthreads();

    if (tid < 256) scanb[tid] = hist[tid];
    __syncthreads();
    for (int off = 1; off < 256; off <<= 1) {
        uint32_t add = 0;
        if (tid < 256 && tid >= off) add = scanb[tid - off];
        __syncthreads();
        if (tid < 256) scanb[tid] += add;
        __syncthreads();
    }
    if (tid < 256) running[tid] = (tid == 0) ? 0u : scanb[tid - 1];
    __syncthreads();

    const int numTiles = (N + BLK - 1) / BLK;
    for (int t = 0; t < numTiles; ++t) {
        for (int j = tid; j < NWAVE * 256; j += BLK) ((uint32_t*)waveCnt)[j] = 0;
        __syncthreads();

        const int i = t * BLK + tid;
        const bool valid = (i < N);
        uint32_t idx = 0, d = 0;
        if (valid) {
            idx = (SHIFT == 0) ? (uint32_t)i : src[base + i];
            d = (sort_key(wts[base + idx]) >> SHIFT) & 255u;
        }
        unsigned long long peers = __ballot(valid);
        #pragma unroll
        for (int b = 0; b < 8; ++b) {
            unsigned long long bit = __ballot(valid && ((d >> b) & 1u));
            peers &= ((d >> b) & 1u) ? bit : ~bit;
        }
        const unsigned long long lower = peers & ((1ull << lane) - 1ull);
        const uint32_t rank = (uint32_t)__popcll(lower);
        if (valid && lower == 0ull) waveCnt[wv][d] = (uint32_t)__popcll(peers);
        __syncthreads();

        if (tid < 256) {
            uint32_t s = running[tid];
            #pragma unroll
            for (int w = 0; w < NWAVE; ++w) {
                uint32_t c = waveCnt[w][tid];
                waveCnt[w][tid] = s;
                s += c;
            }
            running[tid] = s;
        }
        __syncthreads();

        if (valid) {
            uint32_t pos = waveCnt[wv][d] + rank;
            dst[base + pos] = idx;
        }
        __syncthreads();
    }
}

__global__ __launch_bounds__(BLK) void finalize_fb(const float* __restrict__ wts,
                                                   const uint32_t* __restrict__ sidx,
                                                   float* __restrict__ out0,
                                                   float* __restrict__ out1,
                                                   float* __restrict__ out2) {
    __shared__ float waveSum[NWAVE];
    __shared__ int   waveFirst[NWAVE];
    __shared__ float waveCum[NWAVE];
    __shared__ int   s_k;
    __shared__ float s_total;

    const int row = blockIdx.x;
    const size_t base = (size_t)row * N;
    const int tid  = threadIdx.x;
    const int lane = tid & 63;
    const int wv   = tid >> 6;

    if (tid == 0) { s_k = -1; s_total = 0.f; }
    __syncthreads();

    float carry = 0.f;
    const int numTiles = (N + BLK - 1) / BLK;
    for (int t = 0; t < numTiles; ++t) {
        const int i = t * BLK + tid;
        const bool valid = (i < N);
        float w = valid ? wts[base + sidx[base + i]] : 0.f;

        float s = w;
        #pragma unroll
        for (int o = 1; o < 64; o <<= 1) {
            float u = __shfl_up(s, o);
            if (lane >= o) s += u;
        }
        if (lane == 63) waveSum[wv] = s;
        __syncthreads();

        float prefix = 0.f, blockTot = 0.f;
        #pragma unroll
        for (int w2 = 0; w2 < NWAVE; ++w2) {
            float t2 = waveSum[w2];
            if (w2 < wv) prefix += t2;
            blockTot += t2;
        }
        const float cum = carry + prefix + s;

        const bool exceed = valid && (cum > THRESH);
        const unsigned long long bal = __ballot(exceed);
        const int fl = (bal == 0ull) ? 64 : (__ffsll(bal) - 1);
        if (lane == 0) waveFirst[wv] = fl;
        if (fl < 64 && lane == fl) waveCum[wv] = cum;
        __syncthreads();
        if (tid == 0) {
            for (int w2 = 0; w2 < NWAVE; ++w2) {
                if (waveFirst[w2] < 64) {
                    s_k = t * BLK + w2 * 64 + waveFirst[w2] + 1;
                    s_total = waveCum[w2];
                    break;
                }
            }
        }
        __syncthreads();
        if (s_k >= 0) break;
        carry += blockTot;
        __syncthreads();
    }

    int k = s_k;
    float total = s_total;
    if (k < 0) { k = N; total = carry; }

    for (int i = tid; i < N; i += BLK) {
        const uint32_t idx = sidx[base + i];
        const float w = wts[base + idx];
        out0[base + i] = (float)idx;
        out1[base + i] = (i < k) ? (w / total) : 0.f;
    }
    if (tid == 0) out2[row] = (float)k;
}

// ---------------------------------------------------------------------------

extern "C" void kernel_launch(void* const* d_in, const int* in_sizes, int n_in,
                              void* d_out, int out_size, void* d_ws, size_t ws_size,
                              hipStream_t stream) {
    const float* wts = (const float*)d_in[0];
    float* out0 = (float*)d_out;                       // sorted_idx (as f32)
    float* out1 = out0 + (size_t)B * N;                // norm_w
    float* out2 = out0 + 2 * (size_t)B * N;            // k (as f32)

    const size_t KEY_BYTES  = (size_t)B * N * 4;       // 102,926,336
    const size_t IDX_BYTES  = (size_t)B * N * 2;       //  51,463,168
    const size_t HIST_BYTES = (size_t)B * 4 * 256 * 4; //   2,097,152
    const size_t KT_BYTES   = (size_t)B * sizeof(KT);
    const size_t WS_NEED = KEY_BYTES + IDX_BYTES + HIST_BYTES + KT_BYTES;

    dim3 g(B), b(BLK);
    if (ws_size >= WS_NEED) {
        uint8_t* ws = (uint8_t*)d_ws;
        uint32_t* keyWS  = (uint32_t*)ws;
        uint16_t* idxWS  = (uint16_t*)(ws + KEY_BYTES);
        uint32_t* histWS = (uint32_t*)(ws + KEY_BYTES + IDX_BYTES);
        KT*       kt     = (KT*)(ws + KEY_BYTES + IDX_BYTES + HIST_BYTES);
        uint32_t* keyOUT = (uint32_t*)out0;            // ping-pong partner in d_out
        uint16_t* idxOUT = (uint16_t*)out1;

        hist4<<<g, b, 0, stream>>>(wts, histWS);
        scatter_pass<0,  true,  false><<<g, b, 0, stream>>>(wts, nullptr, nullptr, keyWS, idxWS, nullptr, nullptr, histWS);
        scatter_pass<8,  false, false><<<g, b, 0, stream>>>(wts, keyWS, idxWS, keyOUT, idxOUT, nullptr, nullptr, histWS);
        scatter_pass<16, false, false><<<g, b, 0, stream>>>(wts, keyOUT, idxOUT, keyWS, idxWS, nullptr, nullptr, histWS);
        scatter_pass<24, false, true ><<<g, b, 0, stream>>>(wts, keyWS, idxWS, nullptr, nullptr, (uint32_t*)out0, out1, histWS);
        scan_k<<<g, b, 0, stream>>>(out1, kt, out2);
        dim3 gn((N + BLK - 1) / BLK, B);
        finalize_norm<<<gn, b, 0, stream>>>((const uint32_t*)out0, out0, out1, kt);
    } else {
        // Fallback: in-place ping-pong inside d_out (round-1 proven path).
        uint32_t* bufA = (uint32_t*)out0;
        uint32_t* bufB = (uint32_t*)out1;
        radix_pass_fb<0 ><<<g, b, 0, stream>>>(wts, nullptr, bufA);
        radix_pass_fb<8 ><<<g, b, 0, stream>>>(wts, bufA, bufB);
        radix_pass_fb<16><<<g, b, 0, stream>>>(wts, bufB, bufA);
        radix_pass_fb<24><<<g, b, 0, stream>>>(wts, bufA, bufB);
        finalize_fb<<<g, b, 0, stream>>>(wts, bufB, out0, out1, out2);
    }
}

// Round 3
// 1041.107 us; speedup vs baseline: 2.7430x; 1.4482x over previous
//
#include <hip/hip_runtime.h>
#include <stdint.h>

#define B    512
#define N    50257
#define BLK  512
#define NWAVE (BLK / 64)
#define TILE 8192
#define NSUB (TILE / BLK)   // 16
#define THRESH 0.4f

// Softmax weights are strictly positive floats: raw bit pattern is monotone
// in value. Complement -> ascending stable order == descending weight order
// with ties broken by ascending original index (LSD radix is stable),
// matching jnp.argsort(-weights).
__device__ __forceinline__ uint32_t sort_key(float w) {
    return ~__float_as_uint(w);
}

struct KT { uint32_t k; float total; };

// ballot-aggregated histogram add (one atomic per distinct digit per wave)
__device__ __forceinline__ void hist_add_matched(uint32_t* bins, uint32_t d, bool valid) {
    unsigned long long peers = __ballot(valid);
    #pragma unroll
    for (int b = 0; b < 8; ++b) {
        unsigned long long bit = __ballot(valid && ((d >> b) & 1u));
        peers &= ((d >> b) & 1u) ? bit : ~bit;
    }
    if (valid) {
        const int lane = threadIdx.x & 63;
        const unsigned long long lower = peers & ((1ull << lane) - 1ull);
        if (lower == 0ull) atomicAdd(&bins[d], (uint32_t)__popcll(peers));
    }
}

// One block per row: all 4 digit histograms in one sequential read, then
// exclusive-scan each into bucket-start offsets.
__global__ __launch_bounds__(BLK) void hist4(const float* __restrict__ wts,
                                             uint32_t* __restrict__ histWS) {
    __shared__ uint32_t h[4][256];
    __shared__ uint32_t sc[256];
    const int row = blockIdx.x;
    const size_t base = (size_t)row * N;
    const int tid = threadIdx.x;

    for (int j = tid; j < 4 * 256; j += BLK) ((uint32_t*)h)[j] = 0;
    __syncthreads();

    const int iters = (N + BLK - 1) / BLK;
    for (int it = 0; it < iters; ++it) {
        const int i = it * BLK + tid;
        const bool valid = (i < N);
        const uint32_t key = valid ? sort_key(wts[base + i]) : 0u;
        if (valid) {
            atomicAdd(&h[0][key & 255u], 1u);           // ~uniform digits
            atomicAdd(&h[1][(key >> 8) & 255u], 1u);
        }
        hist_add_matched(h[2], (key >> 16) & 255u, valid);  // skewed digits
        hist_add_matched(h[3], (key >> 24) & 255u, valid);
    }
    __syncthreads();

    for (int p = 0; p < 4; ++p) {
        if (tid < 256) sc[tid] = h[p][tid];
        __syncthreads();
        for (int off = 1; off < 256; off <<= 1) {
            uint32_t add = 0;
            if (tid < 256 && tid >= off) add = sc[tid - off];
            __syncthreads();
            if (tid < 256) sc[tid] += add;
            __syncthreads();
        }
        if (tid < 256)
            histWS[((size_t)row * 4 + p) * 256 + tid] = (tid == 0) ? 0u : sc[tid - 1];
        __syncthreads();
    }
}

// LDS-staged stable LSD scatter pass. Ranks a whole 8192-elem tile, stages it
// bucket-contiguous in LDS, then flushes per-bucket contiguous runs to global
// (avg run = TILE/256 = 32 elems = 192B -> write amplification ~1.3x instead
// of ~7x for direct 6B scatter).
template <int SHIFT, bool FIRST, bool LAST>
__global__ __launch_bounds__(BLK, 4) void scatter_tile(const float* __restrict__ wts,
                                                       const uint32_t* __restrict__ keySrc,
                                                       const uint16_t* __restrict__ idxSrc,
                                                       uint32_t* __restrict__ keyDst,
                                                       uint16_t* __restrict__ idxDst,
                                                       uint32_t* __restrict__ outIdx,
                                                       float* __restrict__ outW,
                                                       const uint32_t* __restrict__ histWS) {
    __shared__ uint32_t stageKey[TILE];        // 32 KB
    __shared__ uint16_t stageIdx[TILE];        // 16 KB
    __shared__ uint32_t waveCnt[NWAVE][256];   //  8 KB
    __shared__ uint16_t subOff[NSUB][256];     //  8 KB
    __shared__ uint32_t cursor[256];
    __shared__ uint32_t tileCnt[256];
    __shared__ uint32_t tileStart[256];
    __shared__ uint32_t scanb[256];

    const int row = blockIdx.x;
    const size_t base = (size_t)row * N;
    const int tid  = threadIdx.x;
    const int lane = tid & 63;
    const int wv   = tid >> 6;
    constexpr int PASS = SHIFT / 8;

    if (tid < 256) cursor[tid] = histWS[((size_t)row * 4 + PASS) * 256 + tid];

    const int numTiles = (N + TILE - 1) / TILE;   // 7
    for (int t = 0; t < numTiles; ++t) {
        const int tbase = t * TILE;
        const int tileLen = (N - tbase < TILE) ? (N - tbase) : TILE;

        uint32_t keyR[NSUB];
        uint32_t idxR[NSUB];
        uint32_t posR[NSUB];

        // ---- Phase 1: rank each subtile; cache key/idx/pos in registers ----
        #pragma unroll
        for (int s = 0; s < NSUB; ++s) {
            for (int j = tid; j < NWAVE * 256; j += BLK) ((uint32_t*)waveCnt)[j] = 0;
            __syncthreads();

            const int i = tbase + s * BLK + tid;
            const bool valid = (i < N);
            uint32_t key = 0, idx = 0, d = 0;
            if (valid) {
                if (FIRST) { key = sort_key(wts[base + i]); idx = (uint32_t)i; }
                else       { key = keySrc[base + i]; idx = (uint32_t)idxSrc[base + i]; }
                d = (key >> SHIFT) & 255u;
            }
            keyR[s] = key;
            if (!FIRST) idxR[s] = idx;

            unsigned long long peers = __ballot(valid);
            #pragma unroll
            for (int b = 0; b < 8; ++b) {
                unsigned long long bit = __ballot(valid && ((d >> b) & 1u));
                peers &= ((d >> b) & 1u) ? bit : ~bit;
            }
            const unsigned long long lower = peers & ((1ull << lane) - 1ull);
            const uint32_t rank = (uint32_t)__popcll(lower);
            if (valid && lower == 0ull) waveCnt[wv][d] = (uint32_t)__popcll(peers);
            __syncthreads();

            if (tid < 256) {
                uint32_t x = 0;
                #pragma unroll
                for (int w = 0; w < NWAVE; ++w) {
                    uint32_t c = waveCnt[w][tid];
                    waveCnt[w][tid] = x;
                    x += c;
                }
                subOff[s][tid] = (uint16_t)x;     // subtile digit count (for now)
            }
            __syncthreads();

            posR[s] = valid ? (waveCnt[wv][d] + rank) : 0u;   // pos within subtile
            __syncthreads();                                   // before re-zeroing
        }

        // ---- Phase 2: per-digit scan across subtiles, then across digits ----
        if (tid < 256) {
            uint32_t run = 0;
            #pragma unroll
            for (int s = 0; s < NSUB; ++s) {
                uint32_t c = subOff[s][tid];
                subOff[s][tid] = (uint16_t)run;   // exclusive offset within tile
                run += c;
            }
            tileCnt[tid] = run;
            scanb[tid] = run;
        }
        __syncthreads();
        for (int off = 1; off < 256; off <<= 1) {
            uint32_t add = 0;
            if (tid < 256 && tid >= off) add = scanb[tid - off];
            __syncthreads();
            if (tid < 256) scanb[tid] += add;
            __syncthreads();
        }
        if (tid < 256) tileStart[tid] = (tid == 0) ? 0u : scanb[tid - 1];
        __syncthreads();

        // ---- Phase 3: stage tile bucket-contiguous in LDS ----
        #pragma unroll
        for (int s = 0; s < NSUB; ++s) {
            const int i = tbase + s * BLK + tid;
            if (i < N) {
                const uint32_t d = (keyR[s] >> SHIFT) & 255u;
                const uint32_t pos = tileStart[d] + (uint32_t)subOff[s][d] + posR[s];
                stageKey[pos] = keyR[s];
                stageIdx[pos] = (uint16_t)(FIRST ? (uint32_t)i : idxR[s]);
            }
        }
        __syncthreads();

        // ---- Phase 4: flush — per-bucket contiguous runs to global ----
        for (int p = tid; p < tileLen; p += BLK) {
            const uint32_t k = stageKey[p];
            const uint32_t d = (k >> SHIFT) & 255u;
            const uint32_t g = cursor[d] + (uint32_t)p - tileStart[d];
            if (LAST) {
                outIdx[base + g] = (uint32_t)stageIdx[p];
                outW[base + g]   = __uint_as_float(~k);
            } else {
                keyDst[base + g] = k;
                idxDst[base + g] = stageIdx[p];
            }
        }
        __syncthreads();
        if (tid < 256) cursor[tid] += tileCnt[tid];
        __syncthreads();
    }
}

// Per-row sequential scan over sorted weights with early exit.
__global__ __launch_bounds__(BLK) void scan_k(const float* __restrict__ sortedW,
                                              KT* __restrict__ kt,
                                              float* __restrict__ out2) {
    __shared__ float waveSum[NWAVE];
    __shared__ int   waveFirst[NWAVE];
    __shared__ float waveCum[NWAVE];
    __shared__ int   s_k;
    __shared__ float s_total;

    const int row = blockIdx.x;
    const size_t base = (size_t)row * N;
    const int tid  = threadIdx.x;
    const int lane = tid & 63;
    const int wv   = tid >> 6;

    if (tid == 0) { s_k = -1; s_total = 0.f; }
    __syncthreads();

    float carry = 0.f;
    const int numTiles = (N + BLK - 1) / BLK;
    for (int t = 0; t < numTiles; ++t) {
        const int i = t * BLK + tid;
        const bool valid = (i < N);
        float w = valid ? sortedW[base + i] : 0.f;

        float s = w;
        #pragma unroll
        for (int o = 1; o < 64; o <<= 1) {
            float u = __shfl_up(s, o);
            if (lane >= o) s += u;
        }
        if (lane == 63) waveSum[wv] = s;
        __syncthreads();

        float prefix = 0.f, blockTot = 0.f;
        #pragma unroll
        for (int w2 = 0; w2 < NWAVE; ++w2) {
            float t2 = waveSum[w2];
            if (w2 < wv) prefix += t2;
            blockTot += t2;
        }
        const float cum = carry + prefix + s;

        const bool exceed = valid && (cum > THRESH);
        const unsigned long long bal = __ballot(exceed);
        const int fl = (bal == 0ull) ? 64 : (__ffsll(bal) - 1);
        if (lane == 0) waveFirst[wv] = fl;
        if (fl < 64 && lane == fl) waveCum[wv] = cum;
        __syncthreads();
        if (tid == 0) {
            for (int w2 = 0; w2 < NWAVE; ++w2) {
                if (waveFirst[w2] < 64) {
                    s_k = t * BLK + w2 * 64 + waveFirst[w2] + 1;
                    s_total = waveCum[w2];
                    break;
                }
            }
        }
        __syncthreads();
        if (s_k >= 0) break;
        carry += blockTot;
        __syncthreads();
    }

    if (tid == 0) {
        int k = s_k;
        float total = s_total;
        if (k < 0) { k = N; total = carry; }
        kt[row].k = (uint32_t)k;
        kt[row].total = total;
        out2[row] = (float)k;
    }
}

// Fully parallel elementwise finalize: idx u32 -> float in place, normalize w.
__global__ __launch_bounds__(BLK) void finalize_norm(const uint32_t* __restrict__ idxU,
                                                     float* __restrict__ out0,
                                                     float* __restrict__ out1,
                                                     const KT* __restrict__ kt) {
    const int row = blockIdx.y;
    const int i = blockIdx.x * BLK + threadIdx.x;
    if (i >= N) return;
    const size_t base = (size_t)row * N;
    const KT p = kt[row];
    const uint32_t idx = idxU[base + i];
    const float w = out1[base + i];
    out0[base + i] = (float)idx;
    out1[base + i] = ((uint32_t)i < p.k) ? (w / p.total) : 0.f;
}

// ---------------------------------------------------------------------------
// FALLBACK PATH (round-2 proven, gather-based): used when d_ws is too small.
// ---------------------------------------------------------------------------

template <int SHIFT>
__global__ __launch_bounds__(BLK) void radix_pass_fb(const float* __restrict__ wts,
                                                     const uint32_t* __restrict__ src,
                                                     uint32_t* __restrict__ dst) {
    __shared__ uint32_t hist[256];
    __shared__ uint32_t scanb[256];
    __shared__ uint32_t running[256];
    __shared__ uint32_t waveCnt[NWAVE][256];

    const int row = blockIdx.x;
    const size_t base = (size_t)row * N;
    const int tid  = threadIdx.x;
    const int lane = tid & 63;
    const int wv   = tid >> 6;

    if (tid < 256) hist[tid] = 0;
    __syncthreads();
    for (int i = tid; i < N; i += BLK) {
        uint32_t idx = (SHIFT == 0) ? (uint32_t)i : src[base + i];
        uint32_t d = (sort_key(wts[base + idx]) >> SHIFT) & 255u;
        atomicAdd(&hist[d], 1u);
    }
    __syncthreads();

    if (tid < 256) scanb[tid] = hist[tid];
    __syncthreads();
    for (int off = 1; off < 256; off <<= 1) {
        uint32_t add = 0;
        if (tid < 256 && tid >= off) add = scanb[tid - off];
        __syncthreads();
        if (tid < 256) scanb[tid] += add;
        __syncthreads();
    }
    if (tid < 256) running[tid] = (tid == 0) ? 0u : scanb[tid - 1];
    __syncthreads();

    const int numTiles = (N + BLK - 1) / BLK;
    for (int t = 0; t < numTiles; ++t) {
        for (int j = tid; j < NWAVE * 256; j += BLK) ((uint32_t*)waveCnt)[j] = 0;
        __syncthreads();

        const int i = t * BLK + tid;
        const bool valid = (i < N);
        uint32_t idx = 0, d = 0;
        if (valid) {
            idx = (SHIFT == 0) ? (uint32_t)i : src[base + i];
            d = (sort_key(wts[base + idx]) >> SHIFT) & 255u;
        }
        unsigned long long peers = __ballot(valid);
        #pragma unroll
        for (int b = 0; b < 8; ++b) {
            unsigned long long bit = __ballot(valid && ((d >> b) & 1u));
            peers &= ((d >> b) & 1u) ? bit : ~bit;
        }
        const unsigned long long lower = peers & ((1ull << lane) - 1ull);
        const uint32_t rank = (uint32_t)__popcll(lower);
        if (valid && lower == 0ull) waveCnt[wv][d] = (uint32_t)__popcll(peers);
        __syncthreads();

        if (tid < 256) {
            uint32_t s = running[tid];
            #pragma unroll
            for (int w = 0; w < NWAVE; ++w) {
                uint32_t c = waveCnt[w][tid];
                waveCnt[w][tid] = s;
                s += c;
            }
            running[tid] = s;
        }
        __syncthreads();

        if (valid) {
            uint32_t pos = waveCnt[wv][d] + rank;
            dst[base + pos] = idx;
        }
        __syncthreads();
    }
}

__global__ __launch_bounds__(BLK) void finalize_fb(const float* __restrict__ wts,
                                                   const uint32_t* __restrict__ sidx,
                                                   float* __restrict__ out0,
                                                   float* __restrict__ out1,
                                                   float* __restrict__ out2) {
    __shared__ float waveSum[NWAVE];
    __shared__ int   waveFirst[NWAVE];
    __shared__ float waveCum[NWAVE];
    __shared__ int   s_k;
    __shared__ float s_total;

    const int row = blockIdx.x;
    const size_t base = (size_t)row * N;
    const int tid  = threadIdx.x;
    const int lane = tid & 63;
    const int wv   = tid >> 6;

    if (tid == 0) { s_k = -1; s_total = 0.f; }
    __syncthreads();

    float carry = 0.f;
    const int numTiles = (N + BLK - 1) / BLK;
    for (int t = 0; t < numTiles; ++t) {
        const int i = t * BLK + tid;
        const bool valid = (i < N);
        float w = valid ? wts[base + sidx[base + i]] : 0.f;

        float s = w;
        #pragma unroll
        for (int o = 1; o < 64; o <<= 1) {
            float u = __shfl_up(s, o);
            if (lane >= o) s += u;
        }
        if (lane == 63) waveSum[wv] = s;
        __syncthreads();

        float prefix = 0.f, blockTot = 0.f;
        #pragma unroll
        for (int w2 = 0; w2 < NWAVE; ++w2) {
            float t2 = waveSum[w2];
            if (w2 < wv) prefix += t2;
            blockTot += t2;
        }
        const float cum = carry + prefix + s;

        const bool exceed = valid && (cum > THRESH);
        const unsigned long long bal = __ballot(exceed);
        const int fl = (bal == 0ull) ? 64 : (__ffsll(bal) - 1);
        if (lane == 0) waveFirst[wv] = fl;
        if (fl < 64 && lane == fl) waveCum[wv] = cum;
        __syncthreads();
        if (tid == 0) {
            for (int w2 = 0; w2 < NWAVE; ++w2) {
                if (waveFirst[w2] < 64) {
                    s_k = t * BLK + w2 * 64 + waveFirst[w2] + 1;
                    s_total = waveCum[w2];
                    break;
                }
            }
        }
        __syncthreads();
        if (s_k >= 0) break;
        carry += blockTot;
        __syncthreads();
    }

    int k = s_k;
    float total = s_total;
    if (k < 0) { k = N; total = carry; }

    for (int i = tid; i < N; i += BLK) {
        const uint32_t idx = sidx[base + i];
        const float w = wts[base + idx];
        out0[base + i] = (float)idx;
        out1[base + i] = (i < k) ? (w / total) : 0.f;
    }
    if (tid == 0) out2[row] = (float)k;
}

// ---------------------------------------------------------------------------

extern "C" void kernel_launch(void* const* d_in, const int* in_sizes, int n_in,
                              void* d_out, int out_size, void* d_ws, size_t ws_size,
                              hipStream_t stream) {
    const float* wts = (const float*)d_in[0];
    float* out0 = (float*)d_out;                       // sorted_idx (as f32)
    float* out1 = out0 + (size_t)B * N;                // norm_w
    float* out2 = out0 + 2 * (size_t)B * N;            // k (as f32)

    const size_t KEY_BYTES  = (size_t)B * N * 4;
    const size_t IDX_BYTES  = (size_t)B * N * 2;
    const size_t HIST_BYTES = (size_t)B * 4 * 256 * 4;
    const size_t KT_BYTES   = (size_t)B * sizeof(KT);
    const size_t WS_NEED = KEY_BYTES + IDX_BYTES + HIST_BYTES + KT_BYTES;

    dim3 g(B), b(BLK);
    if (ws_size >= WS_NEED) {
        uint8_t* ws = (uint8_t*)d_ws;
        uint32_t* keyWS  = (uint32_t*)ws;
        uint16_t* idxWS  = (uint16_t*)(ws + KEY_BYTES);
        uint32_t* histWS = (uint32_t*)(ws + KEY_BYTES + IDX_BYTES);
        KT*       kt     = (KT*)(ws + KEY_BYTES + IDX_BYTES + HIST_BYTES);
        uint32_t* keyOUT = (uint32_t*)out0;            // ping-pong partner in d_out
        uint16_t* idxOUT = (uint16_t*)out1;

        hist4<<<g, b, 0, stream>>>(wts, histWS);
        scatter_tile<0,  true,  false><<<g, b, 0, stream>>>(wts, nullptr, nullptr, keyWS, idxWS, nullptr, nullptr, histWS);
        scatter_tile<8,  false, false><<<g, b, 0, stream>>>(wts, keyWS, idxWS, keyOUT, idxOUT, nullptr, nullptr, histWS);
        scatter_tile<16, false, false><<<g, b, 0, stream>>>(wts, keyOUT, idxOUT, keyWS, idxWS, nullptr, nullptr, histWS);
        scatter_tile<24, false, true ><<<g, b, 0, stream>>>(wts, keyWS, idxWS, nullptr, nullptr, (uint32_t*)out0, out1, histWS);
        scan_k<<<g, b, 0, stream>>>(out1, kt, out2);
        dim3 gn((N + BLK - 1) / BLK, B);
        finalize_norm<<<gn, b, 0, stream>>>((const uint32_t*)out0, out0, out1, kt);
    } else {
        uint32_t* bufA = (uint32_t*)out0;
        uint32_t* bufB = (uint32_t*)out1;
        radix_pass_fb<0 ><<<g, b, 0, stream>>>(wts, nullptr, bufA);
        radix_pass_fb<8 ><<<g, b, 0, stream>>>(wts, bufA, bufB);
        radix_pass_fb<16><<<g, b, 0, stream>>>(wts, bufB, bufA);
        radix_pass_fb<24><<<g, b, 0, stream>>>(wts, bufA, bufB);
        finalize_fb<<<g, b, 0, stream>>>(wts, bufB, out0, out1, out2);
    }
}

// Round 4
// 808.320 us; speedup vs baseline: 3.5330x; 1.2880x over previous
//
#include <hip/hip_runtime.h>
#include <stdint.h>

#define B    512
#define N    50257
#define BLK  512
#define NWAVE 8
#define TILE 8192
#define CHUNK 1024           // per-wave contiguous chunk = TILE/NWAVE
#define NGRP 16              // 64-elem groups per chunk
#define THRESH 0.4f

// Softmax weights are strictly positive floats: raw bit pattern is monotone
// in value. Complement -> ascending stable order == descending weight order,
// ties broken by ascending original index (stable LSD radix), matching
// jnp.argsort(-weights).
__device__ __forceinline__ uint32_t sort_key(float w) { return ~__float_as_uint(w); }

// 256-bin exclusive scan. MUST be called by all 512 threads (tid>=256 pass 0).
// Two internal barriers (second protects wtot reuse by a later call).
__device__ __forceinline__ uint32_t excl_scan256(uint32_t val, uint32_t* wtot) {
    const int tid = threadIdx.x;
    const int lane = tid & 63;
    uint32_t incl = val;
    #pragma unroll
    for (int o = 1; o < 64; o <<= 1) {
        uint32_t u = __shfl_up(incl, o);
        if (lane >= o) incl += u;
    }
    if (tid < 256 && lane == 63) wtot[tid >> 6] = incl;
    __syncthreads();
    uint32_t prefix = 0;
    if (tid < 256) {
        const int wv = tid >> 6;
        #pragma unroll
        for (int w = 0; w < 4; ++w) if (w < wv) prefix += wtot[w];
    }
    __syncthreads();
    return prefix + incl - val;
}

// ---------------------------------------------------------------------------
// Shared: histogram kernel (per-wave-private bins, plain LDS atomics).
// ---------------------------------------------------------------------------
__global__ __launch_bounds__(BLK) void hist4_fast(const float* __restrict__ wts,
                                                  uint32_t* __restrict__ histWS) {
    __shared__ uint32_t hw[NWAVE][4][256];   // 32 KB
    __shared__ uint32_t wtot[4];
    const int row = blockIdx.x;
    const size_t base = (size_t)row * N;
    const int tid = threadIdx.x;
    const int lane = tid & 63;
    const int wv = tid >> 6;

    {   // zero own wave's slice (no cross-wave access -> no barrier needed)
        uint32_t* p = &hw[wv][0][0];
        for (int j = lane; j < 4 * 256; j += 64) p[j] = 0;
    }

    for (int i = tid; i < N; i += BLK) {
        const uint32_t key = sort_key(wts[base + i]);
        atomicAdd(&hw[wv][0][key & 255u], 1u);
        atomicAdd(&hw[wv][1][(key >> 8) & 255u], 1u);
        atomicAdd(&hw[wv][2][(key >> 16) & 255u], 1u);
        atomicAdd(&hw[wv][3][(key >> 24) & 255u], 1u);
    }
    __syncthreads();

    for (int p = 0; p < 4; ++p) {
        uint32_t cnt = 0;
        if (tid < 256) {
            #pragma unroll
            for (int w = 0; w < NWAVE; ++w) cnt += hw[w][p][tid];
        }
        const uint32_t ex = excl_scan256(cnt, wtot);
        if (tid < 256) histWS[((size_t)row * 4 + p) * 256 + tid] = ex;
    }
}

// ---------------------------------------------------------------------------
// TIER A: wave-private-chunk scatter on packed u64 (key<<16 | idx).
// ---------------------------------------------------------------------------
template <int SHIFT, bool FIRST, bool LAST>
__global__ __launch_bounds__(BLK, 4) void scatter_wp(const float* __restrict__ wts,
                                                     const unsigned long long* __restrict__ src,
                                                     unsigned long long* __restrict__ dst,
                                                     uint32_t* __restrict__ outIdx,
                                                     float* __restrict__ outW,
                                                     const uint32_t* __restrict__ histWS) {
    __shared__ unsigned long long stage[TILE];   // 64 KB
    __shared__ uint32_t waveCnt[NWAVE][256];     //  8 KB
    __shared__ uint32_t delta[256];              //  1 KB
    __shared__ uint32_t wtot[4];

    const int row = blockIdx.x;
    const size_t base = (size_t)row * N;
    const int tid  = threadIdx.x;
    const int lane = tid & 63;
    const int wv   = tid >> 6;
    constexpr int PASS = SHIFT / 8;
    constexpr int KS = SHIFT + 16;   // digit position within packed pair

    uint32_t curReg = 0;             // this thread's bucket cursor (tid<256)
    if (tid < 256) curReg = histWS[((size_t)row * 4 + PASS) * 256 + tid];

    const int numTiles = (N + TILE - 1) / TILE;
    for (int t = 0; t < numTiles; ++t) {
        const int tbase = t * TILE;
        const int tileLen = (N - tbase < TILE) ? (N - tbase) : TILE;

        // ---- Phase 1: wave-private ranking (NO barriers) ----
        {   // zero own wave's 256 counters: one ds_write_b128 per lane
            uint4* z = (uint4*)&waveCnt[wv][0];
            z[lane] = make_uint4(0u, 0u, 0u, 0u);
        }

        unsigned long long pairR[NGRP];
        uint32_t posR[NGRP];
        const int cbase = tbase + wv * CHUNK;

        #pragma unroll
        for (int g = 0; g < NGRP; ++g) {
            const int i = cbase + g * 64 + lane;
            const bool valid = (i < N);
            unsigned long long pair = 0;
            if (valid) {
                if (FIRST) pair = ((unsigned long long)sort_key(wts[base + i]) << 16) | (uint32_t)i;
                else       pair = src[base + i];
            }
            const uint32_t d = (uint32_t)(pair >> KS) & 255u;
            unsigned long long peers = __ballot(valid);
            #pragma unroll
            for (int bb = 0; bb < 8; ++bb) {
                const unsigned long long bit = __ballot((d >> bb) & 1u);
                peers &= ((d >> bb) & 1u) ? bit : ~bit;
            }
            const unsigned long long lower = peers & ((1ull << lane) - 1ull);
            uint32_t cnt = 0;
            if (valid) cnt = waveCnt[wv][d];                 // pre-update count
            posR[g] = cnt + (uint32_t)__popcll(lower);       // stable in-chunk pos
            if (valid && lower == 0ull)                      // group leader updates
                waveCnt[wv][d] = cnt + (uint32_t)__popcll(peers);
            pairR[g] = pair;
        }
        __syncthreads();

        // ---- Phase 2: tile layout (once per tile) ----
        uint32_t run = 0;
        if (tid < 256) {
            #pragma unroll
            for (int w = 0; w < NWAVE; ++w) {
                const uint32_t c = waveCnt[w][tid];
                waveCnt[w][tid] = run;                       // excl offset across waves
                run += c;
            }
        }
        const uint32_t ts = excl_scan256(run, wtot);         // tileStart[tid]
        if (tid < 256) {
            delta[tid] = curReg - ts;                        // global = delta[d] + p
            curReg += run;
            #pragma unroll
            for (int w = 0; w < NWAVE; ++w) waveCnt[w][tid] += ts;
        }
        __syncthreads();

        // ---- Phase 3: stage bucket-contiguous in LDS ----
        #pragma unroll
        for (int g = 0; g < NGRP; ++g) {
            const int i = cbase + g * 64 + lane;
            if (i < N) {
                const uint32_t d = (uint32_t)(pairR[g] >> KS) & 255u;
                stage[waveCnt[wv][d] + posR[g]] = pairR[g];
            }
        }
        __syncthreads();

        // ---- Phase 4: flush contiguous runs to global ----
        for (int p = tid; p < tileLen; p += BLK) {
            const unsigned long long pair = stage[p];
            const uint32_t d = (uint32_t)(pair >> KS) & 255u;
            const uint32_t g = delta[d] + (uint32_t)p;
            if (LAST) {
                outIdx[base + g] = (uint32_t)(pair & 0xFFFFull);
                outW[base + g]   = __uint_as_float(~(uint32_t)(pair >> 16));
            } else {
                dst[base + g] = pair;
            }
        }
        __syncthreads();   // stage/waveCnt reuse next tile
    }
}

// ---------------------------------------------------------------------------
// Shared: merged scan + normalize + idx->float (in place), block per row.
// out0 holds u32 idx, out1 holds sorted w on entry.
// ---------------------------------------------------------------------------
__global__ __launch_bounds__(BLK) void finalize_row(float* __restrict__ out0,
                                                    float* __restrict__ out1,
                                                    float* __restrict__ out2) {
    __shared__ float waveSum[NWAVE];
    __shared__ int   waveFirst[NWAVE];
    __shared__ float waveCum[NWAVE];
    __shared__ int   s_k;
    __shared__ float s_total;

    const int row = blockIdx.x;
    const size_t base = (size_t)row * N;
    const int tid  = threadIdx.x;
    const int lane = tid & 63;
    const int wv   = tid >> 6;

    if (tid == 0) { s_k = -1; s_total = 0.f; }
    __syncthreads();

    // Phase A: block-wide running cumsum with early exit
    float carry = 0.f;
    const int numTiles = (N + BLK - 1) / BLK;
    for (int t = 0; t < numTiles; ++t) {
        const int i = t * BLK + tid;
        const bool valid = (i < N);
        float w = valid ? out1[base + i] : 0.f;

        float s = w;
        #pragma unroll
        for (int o = 1; o < 64; o <<= 1) {
            float u = __shfl_up(s, o);
            if (lane >= o) s += u;
        }
        if (lane == 63) waveSum[wv] = s;
        __syncthreads();

        float prefix = 0.f, blockTot = 0.f;
        #pragma unroll
        for (int w2 = 0; w2 < NWAVE; ++w2) {
            float t2 = waveSum[w2];
            if (w2 < wv) prefix += t2;
            blockTot += t2;
        }
        const float cum = carry + prefix + s;

        const bool exceed = valid && (cum > THRESH);
        const unsigned long long bal = __ballot(exceed);
        const int fl = (bal == 0ull) ? 64 : (__ffsll(bal) - 1);
        if (lane == 0) waveFirst[wv] = fl;
        if (fl < 64 && lane == fl) waveCum[wv] = cum;
        __syncthreads();
        if (tid == 0) {
            for (int w2 = 0; w2 < NWAVE; ++w2) {
                if (waveFirst[w2] < 64) {
                    s_k = t * BLK + w2 * 64 + waveFirst[w2] + 1;
                    s_total = waveCum[w2];
                    break;
                }
            }
        }
        __syncthreads();
        if (s_k >= 0) break;
        carry += blockTot;
        __syncthreads();
    }

    int k = s_k;
    float total = s_total;
    if (k < 0) { k = N; total = carry; }

    // Phase B: in-place convert + normalize (per-thread read-before-write)
    const uint32_t* idxU = (const uint32_t*)out0;
    for (int i = tid; i < N; i += BLK) {
        const uint32_t idx = idxU[base + i];
        const float w = out1[base + i];
        out0[base + i] = (float)idx;
        out1[base + i] = (i < k) ? (w / total) : 0.f;
    }
    if (tid == 0) out2[row] = (float)k;
}

// ---------------------------------------------------------------------------
// TIER B (round-3 proven): subtile-ballot scatter on separate key/idx arrays.
// ---------------------------------------------------------------------------
#define NSUB (TILE / BLK)   // 16

template <int SHIFT, bool FIRST, bool LAST>
__global__ __launch_bounds__(BLK, 4) void scatter_tile(const float* __restrict__ wts,
                                                       const uint32_t* __restrict__ keySrc,
                                                       const uint16_t* __restrict__ idxSrc,
                                                       uint32_t* __restrict__ keyDst,
                                                       uint16_t* __restrict__ idxDst,
                                                       uint32_t* __restrict__ outIdx,
                                                       float* __restrict__ outW,
                                                       const uint32_t* __restrict__ histWS) {
    __shared__ uint32_t stageKey[TILE];
    __shared__ uint16_t stageIdx[TILE];
    __shared__ uint32_t waveCnt[NWAVE][256];
    __shared__ uint16_t subOff[NSUB][256];
    __shared__ uint32_t cursor[256];
    __shared__ uint32_t tileCnt[256];
    __shared__ uint32_t tileStart[256];
    __shared__ uint32_t scanb[256];

    const int row = blockIdx.x;
    const size_t base = (size_t)row * N;
    const int tid  = threadIdx.x;
    const int lane = tid & 63;
    const int wv   = tid >> 6;
    constexpr int PASS = SHIFT / 8;

    if (tid < 256) cursor[tid] = histWS[((size_t)row * 4 + PASS) * 256 + tid];

    const int numTiles = (N + TILE - 1) / TILE;
    for (int t = 0; t < numTiles; ++t) {
        const int tbase = t * TILE;
        const int tileLen = (N - tbase < TILE) ? (N - tbase) : TILE;

        uint32_t keyR[NSUB];
        uint32_t idxR[NSUB];
        uint32_t posR[NSUB];

        #pragma unroll
        for (int s = 0; s < NSUB; ++s) {
            for (int j = tid; j < NWAVE * 256; j += BLK) ((uint32_t*)waveCnt)[j] = 0;
            __syncthreads();

            const int i = tbase + s * BLK + tid;
            const bool valid = (i < N);
            uint32_t key = 0, idx = 0, d = 0;
            if (valid) {
                if (FIRST) { key = sort_key(wts[base + i]); idx = (uint32_t)i; }
                else       { key = keySrc[base + i]; idx = (uint32_t)idxSrc[base + i]; }
                d = (key >> SHIFT) & 255u;
            }
            keyR[s] = key;
            if (!FIRST) idxR[s] = idx;

            unsigned long long peers = __ballot(valid);
            #pragma unroll
            for (int b = 0; b < 8; ++b) {
                unsigned long long bit = __ballot(valid && ((d >> b) & 1u));
                peers &= ((d >> b) & 1u) ? bit : ~bit;
            }
            const unsigned long long lower = peers & ((1ull << lane) - 1ull);
            const uint32_t rank = (uint32_t)__popcll(lower);
            if (valid && lower == 0ull) waveCnt[wv][d] = (uint32_t)__popcll(peers);
            __syncthreads();

            if (tid < 256) {
                uint32_t x = 0;
                #pragma unroll
                for (int w = 0; w < NWAVE; ++w) {
                    uint32_t c = waveCnt[w][tid];
                    waveCnt[w][tid] = x;
                    x += c;
                }
                subOff[s][tid] = (uint16_t)x;
            }
            __syncthreads();

            posR[s] = valid ? (waveCnt[wv][d] + rank) : 0u;
            __syncthreads();
        }

        if (tid < 256) {
            uint32_t run = 0;
            #pragma unroll
            for (int s = 0; s < NSUB; ++s) {
                uint32_t c = subOff[s][tid];
                subOff[s][tid] = (uint16_t)run;
                run += c;
            }
            tileCnt[tid] = run;
            scanb[tid] = run;
        }
        __syncthreads();
        for (int off = 1; off < 256; off <<= 1) {
            uint32_t add = 0;
            if (tid < 256 && tid >= off) add = scanb[tid - off];
            __syncthreads();
            if (tid < 256) scanb[tid] += add;
            __syncthreads();
        }
        if (tid < 256) tileStart[tid] = (tid == 0) ? 0u : scanb[tid - 1];
        __syncthreads();

        #pragma unroll
        for (int s = 0; s < NSUB; ++s) {
            const int i = tbase + s * BLK + tid;
            if (i < N) {
                const uint32_t d = (keyR[s] >> SHIFT) & 255u;
                const uint32_t pos = tileStart[d] + (uint32_t)subOff[s][d] + posR[s];
                stageKey[pos] = keyR[s];
                stageIdx[pos] = (uint16_t)(FIRST ? (uint32_t)i : idxR[s]);
            }
        }
        __syncthreads();

        for (int p = tid; p < tileLen; p += BLK) {
            const uint32_t k = stageKey[p];
            const uint32_t d = (k >> SHIFT) & 255u;
            const uint32_t g = cursor[d] + (uint32_t)p - tileStart[d];
            if (LAST) {
                outIdx[base + g] = (uint32_t)stageIdx[p];
                outW[base + g]   = __uint_as_float(~k);
            } else {
                keyDst[base + g] = k;
                idxDst[base + g] = stageIdx[p];
            }
        }
        __syncthreads();
        if (tid < 256) cursor[tid] += tileCnt[tid];
        __syncthreads();
    }
}

// ---------------------------------------------------------------------------
// TIER C (round-1 proven): gather-based fallback, no workspace.
// ---------------------------------------------------------------------------
template <int SHIFT>
__global__ __launch_bounds__(BLK) void radix_pass_fb(const float* __restrict__ wts,
                                                     const uint32_t* __restrict__ src,
                                                     uint32_t* __restrict__ dst) {
    __shared__ uint32_t hist[256];
    __shared__ uint32_t scanb[256];
    __shared__ uint32_t running[256];
    __shared__ uint32_t waveCnt[NWAVE][256];

    const int row = blockIdx.x;
    const size_t base = (size_t)row * N;
    const int tid  = threadIdx.x;
    const int lane = tid & 63;
    const int wv   = tid >> 6;

    if (tid < 256) hist[tid] = 0;
    __syncthreads();
    for (int i = tid; i < N; i += BLK) {
        uint32_t idx = (SHIFT == 0) ? (uint32_t)i : src[base + i];
        uint32_t d = (sort_key(wts[base + idx]) >> SHIFT) & 255u;
        atomicAdd(&hist[d], 1u);
    }
    __syncthreads();

    if (tid < 256) scanb[tid] = hist[tid];
    __syncthreads();
    for (int off = 1; off < 256; off <<= 1) {
        uint32_t add = 0;
        if (tid < 256 && tid >= off) add = scanb[tid - off];
        __syncthreads();
        if (tid < 256) scanb[tid] += add;
        __syncthreads();
    }
    if (tid < 256) running[tid] = (tid == 0) ? 0u : scanb[tid - 1];
    __syncthreads();

    const int numTiles = (N + BLK - 1) / BLK;
    for (int t = 0; t < numTiles; ++t) {
        for (int j = tid; j < NWAVE * 256; j += BLK) ((uint32_t*)waveCnt)[j] = 0;
        __syncthreads();

        const int i = t * BLK + tid;
        const bool valid = (i < N);
        uint32_t idx = 0, d = 0;
        if (valid) {
            idx = (SHIFT == 0) ? (uint32_t)i : src[base + i];
            d = (sort_key(wts[base + idx]) >> SHIFT) & 255u;
        }
        unsigned long long peers = __ballot(valid);
        #pragma unroll
        for (int b = 0; b < 8; ++b) {
            unsigned long long bit = __ballot(valid && ((d >> b) & 1u));
            peers &= ((d >> b) & 1u) ? bit : ~bit;
        }
        const unsigned long long lower = peers & ((1ull << lane) - 1ull);
        const uint32_t rank = (uint32_t)__popcll(lower);
        if (valid && lower == 0ull) waveCnt[wv][d] = (uint32_t)__popcll(peers);
        __syncthreads();

        if (tid < 256) {
            uint32_t s = running[tid];
            #pragma unroll
            for (int w = 0; w < NWAVE; ++w) {
                uint32_t c = waveCnt[w][tid];
                waveCnt[w][tid] = s;
                s += c;
            }
            running[tid] = s;
        }
        __syncthreads();

        if (valid) {
            uint32_t pos = waveCnt[wv][d] + rank;
            dst[base + pos] = idx;
        }
        __syncthreads();
    }
}

__global__ __launch_bounds__(BLK) void finalize_fb(const float* __restrict__ wts,
                                                   const uint32_t* __restrict__ sidx,
                                                   float* __restrict__ out0,
                                                   float* __restrict__ out1,
                                                   float* __restrict__ out2) {
    __shared__ float waveSum[NWAVE];
    __shared__ int   waveFirst[NWAVE];
    __shared__ float waveCum[NWAVE];
    __shared__ int   s_k;
    __shared__ float s_total;

    const int row = blockIdx.x;
    const size_t base = (size_t)row * N;
    const int tid  = threadIdx.x;
    const int lane = tid & 63;
    const int wv   = tid >> 6;

    if (tid == 0) { s_k = -1; s_total = 0.f; }
    __syncthreads();

    float carry = 0.f;
    const int numTiles = (N + BLK - 1) / BLK;
    for (int t = 0; t < numTiles; ++t) {
        const int i = t * BLK + tid;
        const bool valid = (i < N);
        float w = valid ? wts[base + sidx[base + i]] : 0.f;

        float s = w;
        #pragma unroll
        for (int o = 1; o < 64; o <<= 1) {
            float u = __shfl_up(s, o);
            if (lane >= o) s += u;
        }
        if (lane == 63) waveSum[wv] = s;
        __syncthreads();

        float prefix = 0.f, blockTot = 0.f;
        #pragma unroll
        for (int w2 = 0; w2 < NWAVE; ++w2) {
            float t2 = waveSum[w2];
            if (w2 < wv) prefix += t2;
            blockTot += t2;
        }
        const float cum = carry + prefix + s;

        const bool exceed = valid && (cum > THRESH);
        const unsigned long long bal = __ballot(exceed);
        const int fl = (bal == 0ull) ? 64 : (__ffsll(bal) - 1);
        if (lane == 0) waveFirst[wv] = fl;
        if (fl < 64 && lane == fl) waveCum[wv] = cum;
        __syncthreads();
        if (tid == 0) {
            for (int w2 = 0; w2 < NWAVE; ++w2) {
                if (waveFirst[w2] < 64) {
                    s_k = t * BLK + w2 * 64 + waveFirst[w2] + 1;
                    s_total = waveCum[w2];
                    break;
                }
            }
        }
        __syncthreads();
        if (s_k >= 0) break;
        carry += blockTot;
        __syncthreads();
    }

    int k = s_k;
    float total = s_total;
    if (k < 0) { k = N; total = carry; }

    for (int i = tid; i < N; i += BLK) {
        const uint32_t idx = sidx[base + i];
        const float w = wts[base + idx];
        out0[base + i] = (float)idx;
        out1[base + i] = (i < k) ? (w / total) : 0.f;
    }
    if (tid == 0) out2[row] = (float)k;
}

// ---------------------------------------------------------------------------

extern "C" void kernel_launch(void* const* d_in, const int* in_sizes, int n_in,
                              void* d_out, int out_size, void* d_ws, size_t ws_size,
                              hipStream_t stream) {
    const float* wts = (const float*)d_in[0];
    float* out0 = (float*)d_out;                       // sorted_idx (as f32)
    float* out1 = out0 + (size_t)B * N;                // norm_w
    float* out2 = out0 + 2 * (size_t)B * N;            // k (as f32)

    const size_t PAIR_BYTES = (size_t)B * N * 8;       // 205,852,672
    const size_t KEY_BYTES  = (size_t)B * N * 4;
    const size_t IDX_BYTES  = (size_t)B * N * 2;
    const size_t HIST_BYTES = (size_t)B * 4 * 256 * 4; // 2,097,152
    const size_t WS_A = PAIR_BYTES + HIST_BYTES;
    const size_t WS_B = KEY_BYTES + IDX_BYTES + HIST_BYTES;

    dim3 g(B), b(BLK);
    if (ws_size >= WS_A) {
        // Tier A: packed-u64 wave-private path.
        uint8_t* ws = (uint8_t*)d_ws;
        unsigned long long* pairWS  = (unsigned long long*)ws;
        uint32_t*           histWS  = (uint32_t*)(ws + PAIR_BYTES);
        unsigned long long* pairOUT = (unsigned long long*)d_out;  // 206MB in d_out

        hist4_fast<<<g, b, 0, stream>>>(wts, histWS);
        scatter_wp<0,  true,  false><<<g, b, 0, stream>>>(wts, nullptr, pairWS, nullptr, nullptr, histWS);
        scatter_wp<8,  false, false><<<g, b, 0, stream>>>(nullptr, pairWS, pairOUT, nullptr, nullptr, histWS);
        scatter_wp<16, false, false><<<g, b, 0, stream>>>(nullptr, pairOUT, pairWS, nullptr, nullptr, histWS);
        scatter_wp<24, false, true ><<<g, b, 0, stream>>>(nullptr, pairWS, nullptr, (uint32_t*)out0, out1, histWS);
        finalize_row<<<g, b, 0, stream>>>(out0, out1, out2);
    } else if (ws_size >= WS_B) {
        // Tier B: round-3 proven path (+ faster hist & merged finalize).
        uint8_t* ws = (uint8_t*)d_ws;
        uint32_t* keyWS  = (uint32_t*)ws;
        uint16_t* idxWS  = (uint16_t*)(ws + KEY_BYTES);
        uint32_t* histWS = (uint32_t*)(ws + KEY_BYTES + IDX_BYTES);
        uint32_t* keyOUT = (uint32_t*)out0;
        uint16_t* idxOUT = (uint16_t*)out1;

        hist4_fast<<<g, b, 0, stream>>>(wts, histWS);
        scatter_tile<0,  true,  false><<<g, b, 0, stream>>>(wts, nullptr, nullptr, keyWS, idxWS, nullptr, nullptr, histWS);
        scatter_tile<8,  false, false><<<g, b, 0, stream>>>(wts, keyWS, idxWS, keyOUT, idxOUT, nullptr, nullptr, histWS);
        scatter_tile<16, false, false><<<g, b, 0, stream>>>(wts, keyOUT, idxOUT, keyWS, idxWS, nullptr, nullptr, histWS);
        scatter_tile<24, false, true ><<<g, b, 0, stream>>>(wts, keyWS, idxWS, nullptr, nullptr, (uint32_t*)out0, out1, histWS);
        finalize_row<<<g, b, 0, stream>>>(out0, out1, out2);
    } else {
        // Tier C: no-workspace fallback.
        uint32_t* bufA = (uint32_t*)out0;
        uint32_t* bufB = (uint32_t*)out1;
        radix_pass_fb<0 ><<<g, b, 0, stream>>>(wts, nullptr, bufA);
        radix_pass_fb<8 ><<<g, b, 0, stream>>>(wts, bufA, bufB);
        radix_pass_fb<16><<<g, b, 0, stream>>>(wts, bufB, bufA);
        radix_pass_fb<24><<<g, b, 0, stream>>>(wts, bufA, bufB);
        finalize_fb<<<g, b, 0, stream>>>(wts, bufB, out0, out1, out2);
    }
}

// Round 5
// 632.614 us; speedup vs baseline: 4.5143x; 1.2777x over previous
//
#include <hip/hip_runtime.h>
#include <stdint.h>

#define B    512
#define N    50257
#define BLK  512
#define NWAVE 8
#define TILE 8192
#define CHUNK 1024           // per-wave contiguous chunk = TILE/NWAVE
#define NGRP 16              // 64-elem groups per chunk
#define THRESH 0.4f

// Softmax weights are strictly positive floats: raw bit pattern is monotone
// in value. Complement -> ascending stable order == descending weight order,
// ties broken by ascending original index (stable LSD radix), matching
// jnp.argsort(-weights).
__device__ __forceinline__ uint32_t sort_key(float w) { return ~__float_as_uint(w); }

// ---------------------------------------------------------------------------
// Shared: histogram kernel (per-wave-private bins, plain LDS atomics).
// ---------------------------------------------------------------------------
__global__ __launch_bounds__(BLK) void hist4_fast(const float* __restrict__ wts,
                                                  uint32_t* __restrict__ histWS) {
    __shared__ uint32_t hw[NWAVE][4][256];   // 32 KB
    __shared__ uint32_t wtot[4];
    const int row = blockIdx.x;
    const size_t base = (size_t)row * N;
    const int tid = threadIdx.x;
    const int lane = tid & 63;
    const int wv = tid >> 6;

    {   // zero own wave's slice (no cross-wave access -> no barrier needed)
        uint32_t* p = &hw[wv][0][0];
        for (int j = lane; j < 4 * 256; j += 64) p[j] = 0;
    }

    for (int i = tid; i < N; i += BLK) {
        const uint32_t key = sort_key(wts[base + i]);
        atomicAdd(&hw[wv][0][key & 255u], 1u);
        atomicAdd(&hw[wv][1][(key >> 8) & 255u], 1u);
        atomicAdd(&hw[wv][2][(key >> 16) & 255u], 1u);
        atomicAdd(&hw[wv][3][(key >> 24) & 255u], 1u);
    }
    __syncthreads();

    for (int p = 0; p < 4; ++p) {
        uint32_t cnt = 0;
        if (tid < 256) {
            #pragma unroll
            for (int w = 0; w < NWAVE; ++w) cnt += hw[w][p][tid];
        }
        // exclusive scan over 256 bins: intra-wave shfl + cross-wave via wtot
        uint32_t incl = cnt;
        #pragma unroll
        for (int o = 1; o < 64; o <<= 1) {
            const uint32_t u = __shfl_up(incl, o);
            if (lane >= o) incl += u;
        }
        if (tid < 256 && lane == 63) wtot[tid >> 6] = incl;
        __syncthreads();
        if (tid < 256) {
            uint32_t prefix = 0;
            const int w4 = tid >> 6;
            #pragma unroll
            for (int w2 = 0; w2 < 4; ++w2) if (w2 < w4) prefix += wtot[w2];
            histWS[((size_t)row * 4 + p) * 256 + tid] = prefix + incl - cnt;
        }
        __syncthreads();   // protect wtot reuse
    }
}

// ---------------------------------------------------------------------------
// TIER A: software-pipelined wave-private scatter on packed u64 (key<<16|idx).
// Per tile: rank from prefetched registers (no barriers, no load stalls),
// one shfl-scan layout phase, stage bucket-contiguous in LDS, prefetch next
// tile, flush contiguous runs. 4 barriers/tile.
// ---------------------------------------------------------------------------
template <int SHIFT, bool FIRST, bool LAST>
__global__ __launch_bounds__(BLK, 4) void scatter_pl(const float* __restrict__ wts,
                                                     const unsigned long long* __restrict__ src,
                                                     unsigned long long* __restrict__ dst,
                                                     uint32_t* __restrict__ outIdx,
                                                     float* __restrict__ outW,
                                                     const uint32_t* __restrict__ histWS) {
    __shared__ unsigned long long stage[TILE];   // 64 KB
    __shared__ uint32_t waveCnt[NWAVE][256];     //  8 KB
    __shared__ uint32_t delta[256];              //  1 KB
    __shared__ uint32_t wtot[4];

    const int row = blockIdx.x;
    const size_t base = (size_t)row * N;
    const int tid  = threadIdx.x;
    const int lane = tid & 63;
    const int wv   = tid >> 6;
    constexpr int PASS = SHIFT / 8;
    constexpr int KS = SHIFT + 16;   // digit position within packed pair

    uint32_t curReg = 0;             // this thread's bucket cursor (tid<256)
    if (tid < 256) curReg = histWS[((size_t)row * 4 + PASS) * 256 + tid];

    const int numTiles = (N + TILE - 1) / TILE;

    unsigned long long pairN[NGRP];
    {   // prefetch tile 0 (always full: TILE < N)
        const int cb = wv * CHUNK;
        #pragma unroll
        for (int g = 0; g < NGRP; ++g) {
            const int i = cb + g * 64 + lane;
            pairN[g] = FIRST ? (((unsigned long long)sort_key(wts[base + i]) << 16) | (uint32_t)i)
                             : src[base + i];
        }
    }

    for (int t = 0; t < numTiles; ++t) {
        const int tbase = t * TILE;
        const int tileLen = (N - tbase < TILE) ? (N - tbase) : TILE;
        const int cbase = tbase + wv * CHUNK;
        const bool full = (tbase + TILE <= N);

        // ---- Phase 1: rank own chunk from registers (NO barriers) ----
        // Safe to zero own waveCnt row here: phase 2 of tile t-1 finished
        // reading all rows before barrier (C,t-1) < (D,t-1).
        {
            uint4* z = (uint4*)&waveCnt[wv][0];
            z[lane] = make_uint4(0u, 0u, 0u, 0u);
        }
        unsigned long long pairR[NGRP];
        uint32_t posR[NGRP];
        #pragma unroll
        for (int g = 0; g < NGRP; ++g) pairR[g] = pairN[g];

        if (full) {
            #pragma unroll
            for (int g = 0; g < NGRP; ++g) {
                const uint32_t d = (uint32_t)(pairR[g] >> KS) & 255u;
                unsigned long long peers = ~0ull;
                #pragma unroll
                for (int bb = 0; bb < 8; ++bb) {
                    const unsigned long long bit = __ballot((d >> bb) & 1u);
                    peers &= ((d >> bb) & 1u) ? bit : ~bit;
                }
                const unsigned long long lower = peers & ((1ull << lane) - 1ull);
                const uint32_t cnt = waveCnt[wv][d];
                posR[g] = cnt + (uint32_t)__popcll(lower);
                if (lower == 0ull) waveCnt[wv][d] = cnt + (uint32_t)__popcll(peers);
            }
        } else {
            #pragma unroll
            for (int g = 0; g < NGRP; ++g) {
                const int i = cbase + g * 64 + lane;
                const bool valid = (i < N);
                const uint32_t d = (uint32_t)(pairR[g] >> KS) & 255u;
                unsigned long long peers = __ballot(valid);
                #pragma unroll
                for (int bb = 0; bb < 8; ++bb) {
                    const unsigned long long bit = __ballot((d >> bb) & 1u);
                    peers &= ((d >> bb) & 1u) ? bit : ~bit;
                }
                const unsigned long long lower = peers & ((1ull << lane) - 1ull);
                uint32_t cnt = 0;
                if (valid) cnt = waveCnt[wv][d];
                posR[g] = cnt + (uint32_t)__popcll(lower);
                if (valid && lower == 0ull) waveCnt[wv][d] = cnt + (uint32_t)__popcll(peers);
            }
        }
        __syncthreads();                               // (A) ranks done; stage(t-1) drained

        // ---- Phase 2: tile layout (shfl scan, 2 barriers) ----
        uint32_t run = 0;
        if (tid < 256) {
            #pragma unroll
            for (int w = 0; w < NWAVE; ++w) {
                const uint32_t c = waveCnt[w][tid];
                waveCnt[w][tid] = run;                 // excl offset across waves
                run += c;
            }
        }
        uint32_t incl = run;
        #pragma unroll
        for (int o = 1; o < 64; o <<= 1) {
            const uint32_t u = __shfl_up(incl, o);
            if (lane >= o) incl += u;
        }
        if (tid < 256 && lane == 63) wtot[tid >> 6] = incl;
        __syncthreads();                               // (B)
        if (tid < 256) {
            uint32_t prefix = 0;
            const int w4 = tid >> 6;
            #pragma unroll
            for (int w2 = 0; w2 < 4; ++w2) if (w2 < w4) prefix += wtot[w2];
            const uint32_t ts = prefix + incl - run;   // tileStart[tid]
            delta[tid] = curReg - ts;                  // global = delta[d] + p
            curReg += run;
            #pragma unroll
            for (int w = 0; w < NWAVE; ++w) waveCnt[w][tid] += ts;
        }
        __syncthreads();                               // (C) layout ready

        // ---- Prefetch next tile (latency hides under phases 3-4) ----
        if (t + 1 < numTiles) {
            const int ncb = (t + 1) * TILE + wv * CHUNK;
            if (ncb + CHUNK <= N) {                    // wave-uniform branch
                #pragma unroll
                for (int g = 0; g < NGRP; ++g) {
                    const int i = ncb + g * 64 + lane;
                    pairN[g] = FIRST ? (((unsigned long long)sort_key(wts[base + i]) << 16) | (uint32_t)i)
                                     : src[base + i];
                }
            } else {
                #pragma unroll
                for (int g = 0; g < NGRP; ++g) {
                    const int i = ncb + g * 64 + lane;
                    unsigned long long pair = 0;
                    if (i < N)
                        pair = FIRST ? (((unsigned long long)sort_key(wts[base + i]) << 16) | (uint32_t)i)
                                     : src[base + i];
                    pairN[g] = pair;
                }
            }
        }

        // ---- Phase 3: stage bucket-contiguous in LDS ----
        if (full) {
            #pragma unroll
            for (int g = 0; g < NGRP; ++g) {
                const uint32_t d = (uint32_t)(pairR[g] >> KS) & 255u;
                stage[waveCnt[wv][d] + posR[g]] = pairR[g];
            }
        } else {
            #pragma unroll
            for (int g = 0; g < NGRP; ++g) {
                const int i = cbase + g * 64 + lane;
                if (i < N) {
                    const uint32_t d = (uint32_t)(pairR[g] >> KS) & 255u;
                    stage[waveCnt[wv][d] + posR[g]] = pairR[g];
                }
            }
        }
        __syncthreads();                               // (D) stage complete

        // ---- Phase 4: flush contiguous runs to global ----
        for (int p = tid; p < tileLen; p += BLK) {
            const unsigned long long pair = stage[p];
            const uint32_t d = (uint32_t)(pair >> KS) & 255u;
            const uint32_t g = delta[d] + (uint32_t)p;
            if (LAST) {
                outIdx[base + g] = (uint32_t)(pair & 0xFFFFull);
                outW[base + g]   = __uint_as_float(~(uint32_t)(pair >> 16));
            } else {
                dst[base + g] = pair;
            }
        }
        // no trailing barrier: (A) of the next tile separates flush(t) reads
        // from stage(t+1) writes and delta(t+1) updates.
    }
}

// ---------------------------------------------------------------------------
// Shared: merged scan + normalize + idx->float (in place), block per row.
// out0 holds u32 idx, out1 holds sorted w on entry.
// ---------------------------------------------------------------------------
__global__ __launch_bounds__(BLK) void finalize_row(float* __restrict__ out0,
                                                    float* __restrict__ out1,
                                                    float* __restrict__ out2) {
    __shared__ float waveSum[NWAVE];
    __shared__ int   waveFirst[NWAVE];
    __shared__ float waveCum[NWAVE];
    __shared__ int   s_k;
    __shared__ float s_total;

    const int row = blockIdx.x;
    const size_t base = (size_t)row * N;
    const int tid  = threadIdx.x;
    const int lane = tid & 63;
    const int wv   = tid >> 6;

    if (tid == 0) { s_k = -1; s_total = 0.f; }
    __syncthreads();

    // Phase A: block-wide running cumsum with early exit
    float carry = 0.f;
    const int numTiles = (N + BLK - 1) / BLK;
    for (int t = 0; t < numTiles; ++t) {
        const int i = t * BLK + tid;
        const bool valid = (i < N);
        float w = valid ? out1[base + i] : 0.f;

        float s = w;
        #pragma unroll
        for (int o = 1; o < 64; o <<= 1) {
            float u = __shfl_up(s, o);
            if (lane >= o) s += u;
        }
        if (lane == 63) waveSum[wv] = s;
        __syncthreads();

        float prefix = 0.f, blockTot = 0.f;
        #pragma unroll
        for (int w2 = 0; w2 < NWAVE; ++w2) {
            float t2 = waveSum[w2];
            if (w2 < wv) prefix += t2;
            blockTot += t2;
        }
        const float cum = carry + prefix + s;

        const bool exceed = valid && (cum > THRESH);
        const unsigned long long bal = __ballot(exceed);
        const int fl = (bal == 0ull) ? 64 : (__ffsll(bal) - 1);
        if (lane == 0) waveFirst[wv] = fl;
        if (fl < 64 && lane == fl) waveCum[wv] = cum;
        __syncthreads();
        if (tid == 0) {
            for (int w2 = 0; w2 < NWAVE; ++w2) {
                if (waveFirst[w2] < 64) {
                    s_k = t * BLK + w2 * 64 + waveFirst[w2] + 1;
                    s_total = waveCum[w2];
                    break;
                }
            }
        }
        __syncthreads();
        if (s_k >= 0) break;
        carry += blockTot;
        __syncthreads();
    }

    int k = s_k;
    float total = s_total;
    if (k < 0) { k = N; total = carry; }
    const float inv = 1.0f / total;

    // Phase B: in-place convert + normalize, vectorized 16B (per-thread
    // read-before-write on identical addresses -> safe).
    const uint32_t* idxU = (const uint32_t*)out0;
    const int head = (int)((4 - (base & 3)) & 3);     // to 16B alignment
    const int nvec = (N - head) >> 2;
    const int vend = head + 4 * nvec;

    for (int i = tid; i < head; i += BLK) {           // head (<4 elems)
        const uint32_t idx = idxU[base + i];
        const float w = out1[base + i];
        out0[base + i] = (float)idx;
        out1[base + i] = (i < k) ? (w * inv) : 0.f;
    }
    const uint4*  ivp = (const uint4*)(idxU + base + head);
    float4*       o0v = (float4*)(out0 + base + head);
    float4*       o1v = (float4*)(out1 + base + head);
    for (int v = tid; v < nvec; v += BLK) {
        const uint4  iv = ivp[v];
        const float4 wv4 = o1v[v];
        const int i = head + 4 * v;
        float4 o0, o1;
        o0.x = (float)iv.x; o0.y = (float)iv.y; o0.z = (float)iv.z; o0.w = (float)iv.w;
        o1.x = (i + 0 < k) ? wv4.x * inv : 0.f;
        o1.y = (i + 1 < k) ? wv4.y * inv : 0.f;
        o1.z = (i + 2 < k) ? wv4.z * inv : 0.f;
        o1.w = (i + 3 < k) ? wv4.w * inv : 0.f;
        o0v[v] = o0;
        o1v[v] = o1;
    }
    for (int i = vend + tid; i < N; i += BLK) {       // tail (<4 elems)
        const uint32_t idx = idxU[base + i];
        const float w = out1[base + i];
        out0[base + i] = (float)idx;
        out1[base + i] = (i < k) ? (w * inv) : 0.f;
    }
    if (tid == 0) out2[row] = (float)k;
}

// ---------------------------------------------------------------------------
// TIER B (round-3 proven): subtile-ballot scatter on separate key/idx arrays.
// ---------------------------------------------------------------------------
#define NSUB (TILE / BLK)   // 16

template <int SHIFT, bool FIRST, bool LAST>
__global__ __launch_bounds__(BLK, 4) void scatter_tile(const float* __restrict__ wts,
                                                       const uint32_t* __restrict__ keySrc,
                                                       const uint16_t* __restrict__ idxSrc,
                                                       uint32_t* __restrict__ keyDst,
                                                       uint16_t* __restrict__ idxDst,
                                                       uint32_t* __restrict__ outIdx,
                                                       float* __restrict__ outW,
                                                       const uint32_t* __restrict__ histWS) {
    __shared__ uint32_t stageKey[TILE];
    __shared__ uint16_t stageIdx[TILE];
    __shared__ uint32_t waveCnt[NWAVE][256];
    __shared__ uint16_t subOff[NSUB][256];
    __shared__ uint32_t cursor[256];
    __shared__ uint32_t tileCnt[256];
    __shared__ uint32_t tileStart[256];
    __shared__ uint32_t scanb[256];

    const int row = blockIdx.x;
    const size_t base = (size_t)row * N;
    const int tid  = threadIdx.x;
    const int lane = tid & 63;
    const int wv   = tid >> 6;
    constexpr int PASS = SHIFT / 8;

    if (tid < 256) cursor[tid] = histWS[((size_t)row * 4 + PASS) * 256 + tid];

    const int numTiles = (N + TILE - 1) / TILE;
    for (int t = 0; t < numTiles; ++t) {
        const int tbase = t * TILE;
        const int tileLen = (N - tbase < TILE) ? (N - tbase) : TILE;

        uint32_t keyR[NSUB];
        uint32_t idxR[NSUB];
        uint32_t posR[NSUB];

        #pragma unroll
        for (int s = 0; s < NSUB; ++s) {
            for (int j = tid; j < NWAVE * 256; j += BLK) ((uint32_t*)waveCnt)[j] = 0;
            __syncthreads();

            const int i = tbase + s * BLK + tid;
            const bool valid = (i < N);
            uint32_t key = 0, idx = 0, d = 0;
            if (valid) {
                if (FIRST) { key = sort_key(wts[base + i]); idx = (uint32_t)i; }
                else       { key = keySrc[base + i]; idx = (uint32_t)idxSrc[base + i]; }
                d = (key >> SHIFT) & 255u;
            }
            keyR[s] = key;
            if (!FIRST) idxR[s] = idx;

            unsigned long long peers = __ballot(valid);
            #pragma unroll
            for (int b = 0; b < 8; ++b) {
                unsigned long long bit = __ballot(valid && ((d >> b) & 1u));
                peers &= ((d >> b) & 1u) ? bit : ~bit;
            }
            const unsigned long long lower = peers & ((1ull << lane) - 1ull);
            const uint32_t rank = (uint32_t)__popcll(lower);
            if (valid && lower == 0ull) waveCnt[wv][d] = (uint32_t)__popcll(peers);
            __syncthreads();

            if (tid < 256) {
                uint32_t x = 0;
                #pragma unroll
                for (int w = 0; w < NWAVE; ++w) {
                    uint32_t c = waveCnt[w][tid];
                    waveCnt[w][tid] = x;
                    x += c;
                }
                subOff[s][tid] = (uint16_t)x;
            }
            __syncthreads();

            posR[s] = valid ? (waveCnt[wv][d] + rank) : 0u;
            __syncthreads();
        }

        if (tid < 256) {
            uint32_t run = 0;
            #pragma unroll
            for (int s = 0; s < NSUB; ++s) {
                uint32_t c = subOff[s][tid];
                subOff[s][tid] = (uint16_t)run;
                run += c;
            }
            tileCnt[tid] = run;
            scanb[tid] = run;
        }
        __syncthreads();
        for (int off = 1; off < 256; off <<= 1) {
            uint32_t add = 0;
            if (tid < 256 && tid >= off) add = scanb[tid - off];
            __syncthreads();
            if (tid < 256) scanb[tid] += add;
            __syncthreads();
        }
        if (tid < 256) tileStart[tid] = (tid == 0) ? 0u : scanb[tid - 1];
        __syncthreads();

        #pragma unroll
        for (int s = 0; s < NSUB; ++s) {
            const int i = tbase + s * BLK + tid;
            if (i < N) {
                const uint32_t d = (keyR[s] >> SHIFT) & 255u;
                const uint32_t pos = tileStart[d] + (uint32_t)subOff[s][d] + posR[s];
                stageKey[pos] = keyR[s];
                stageIdx[pos] = (uint16_t)(FIRST ? (uint32_t)i : idxR[s]);
            }
        }
        __syncthreads();

        for (int p = tid; p < tileLen; p += BLK) {
            const uint32_t k = stageKey[p];
            const uint32_t d = (k >> SHIFT) & 255u;
            const uint32_t g = cursor[d] + (uint32_t)p - tileStart[d];
            if (LAST) {
                outIdx[base + g] = (uint32_t)stageIdx[p];
                outW[base + g]   = __uint_as_float(~k);
            } else {
                keyDst[base + g] = k;
                idxDst[base + g] = stageIdx[p];
            }
        }
        __syncthreads();
        if (tid < 256) cursor[tid] += tileCnt[tid];
        __syncthreads();
    }
}

// ---------------------------------------------------------------------------
// TIER C (round-1 proven): gather-based fallback, no workspace.
// ---------------------------------------------------------------------------
template <int SHIFT>
__global__ __launch_bounds__(BLK) void radix_pass_fb(const float* __restrict__ wts,
                                                     const uint32_t* __restrict__ src,
                                                     uint32_t* __restrict__ dst) {
    __shared__ uint32_t hist[256];
    __shared__ uint32_t scanb[256];
    __shared__ uint32_t running[256];
    __shared__ uint32_t waveCnt[NWAVE][256];

    const int row = blockIdx.x;
    const size_t base = (size_t)row * N;
    const int tid  = threadIdx.x;
    const int lane = tid & 63;
    const int wv   = tid >> 6;

    if (tid < 256) hist[tid] = 0;
    __syncthreads();
    for (int i = tid; i < N; i += BLK) {
        uint32_t idx = (SHIFT == 0) ? (uint32_t)i : src[base + i];
        uint32_t d = (sort_key(wts[base + idx]) >> SHIFT) & 255u;
        atomicAdd(&hist[d], 1u);
    }
    __syncthreads();

    if (tid < 256) scanb[tid] = hist[tid];
    __syncthreads();
    for (int off = 1; off < 256; off <<= 1) {
        uint32_t add = 0;
        if (tid < 256 && tid >= off) add = scanb[tid - off];
        __syncthreads();
        if (tid < 256) scanb[tid] += add;
        __syncthreads();
    }
    if (tid < 256) running[tid] = (tid == 0) ? 0u : scanb[tid - 1];
    __syncthreads();

    const int numTiles = (N + BLK - 1) / BLK;
    for (int t = 0; t < numTiles; ++t) {
        for (int j = tid; j < NWAVE * 256; j += BLK) ((uint32_t*)waveCnt)[j] = 0;
        __syncthreads();

        const int i = t * BLK + tid;
        const bool valid = (i < N);
        uint32_t idx = 0, d = 0;
        if (valid) {
            idx = (SHIFT == 0) ? (uint32_t)i : src[base + i];
            d = (sort_key(wts[base + idx]) >> SHIFT) & 255u;
        }
        unsigned long long peers = __ballot(valid);
        #pragma unroll
        for (int b = 0; b < 8; ++b) {
            unsigned long long bit = __ballot(valid && ((d >> b) & 1u));
            peers &= ((d >> b) & 1u) ? bit : ~bit;
        }
        const unsigned long long lower = peers & ((1ull << lane) - 1ull);
        const uint32_t rank = (uint32_t)__popcll(lower);
        if (valid && lower == 0ull) waveCnt[wv][d] = (uint32_t)__popcll(peers);
        __syncthreads();

        if (tid < 256) {
            uint32_t s = running[tid];
            #pragma unroll
            for (int w = 0; w < NWAVE; ++w) {
                uint32_t c = waveCnt[w][tid];
                waveCnt[w][tid] = s;
                s += c;
            }
            running[tid] = s;
        }
        __syncthreads();

        if (valid) {
            uint32_t pos = waveCnt[wv][d] + rank;
            dst[base + pos] = idx;
        }
        __syncthreads();
    }
}

__global__ __launch_bounds__(BLK) void finalize_fb(const float* __restrict__ wts,
                                                   const uint32_t* __restrict__ sidx,
                                                   float* __restrict__ out0,
                                                   float* __restrict__ out1,
                                                   float* __restrict__ out2) {
    __shared__ float waveSum[NWAVE];
    __shared__ int   waveFirst[NWAVE];
    __shared__ float waveCum[NWAVE];
    __shared__ int   s_k;
    __shared__ float s_total;

    const int row = blockIdx.x;
    const size_t base = (size_t)row * N;
    const int tid  = threadIdx.x;
    const int lane = tid & 63;
    const int wv   = tid >> 6;

    if (tid == 0) { s_k = -1; s_total = 0.f; }
    __syncthreads();

    float carry = 0.f;
    const int numTiles = (N + BLK - 1) / BLK;
    for (int t = 0; t < numTiles; ++t) {
        const int i = t * BLK + tid;
        const bool valid = (i < N);
        float w = valid ? wts[base + sidx[base + i]] : 0.f;

        float s = w;
        #pragma unroll
        for (int o = 1; o < 64; o <<= 1) {
            float u = __shfl_up(s, o);
            if (lane >= o) s += u;
        }
        if (lane == 63) waveSum[wv] = s;
        __syncthreads();

        float prefix = 0.f, blockTot = 0.f;
        #pragma unroll
        for (int w2 = 0; w2 < NWAVE; ++w2) {
            float t2 = waveSum[w2];
            if (w2 < wv) prefix += t2;
            blockTot += t2;
        }
        const float cum = carry + prefix + s;

        const bool exceed = valid && (cum > THRESH);
        const unsigned long long bal = __ballot(exceed);
        const int fl = (bal == 0ull) ? 64 : (__ffsll(bal) - 1);
        if (lane == 0) waveFirst[wv] = fl;
        if (fl < 64 && lane == fl) waveCum[wv] = cum;
        __syncthreads();
        if (tid == 0) {
            for (int w2 = 0; w2 < NWAVE; ++w2) {
                if (waveFirst[w2] < 64) {
                    s_k = t * BLK + w2 * 64 + waveFirst[w2] + 1;
                    s_total = waveCum[w2];
                    break;
                }
            }
        }
        __syncthreads();
        if (s_k >= 0) break;
        carry += blockTot;
        __syncthreads();
    }

    int k = s_k;
    float total = s_total;
    if (k < 0) { k = N; total = carry; }

    for (int i = tid; i < N; i += BLK) {
        const uint32_t idx = sidx[base + i];
        const float w = wts[base + idx];
        out0[base + i] = (float)idx;
        out1[base + i] = (i < k) ? (w / total) : 0.f;
    }
    if (tid == 0) out2[row] = (float)k;
}

// ---------------------------------------------------------------------------

extern "C" void kernel_launch(void* const* d_in, const int* in_sizes, int n_in,
                              void* d_out, int out_size, void* d_ws, size_t ws_size,
                              hipStream_t stream) {
    const float* wts = (const float*)d_in[0];
    float* out0 = (float*)d_out;                       // sorted_idx (as f32)
    float* out1 = out0 + (size_t)B * N;                // norm_w
    float* out2 = out0 + 2 * (size_t)B * N;            // k (as f32)

    const size_t PAIR_BYTES = (size_t)B * N * 8;       // 205,852,672
    const size_t KEY_BYTES  = (size_t)B * N * 4;
    const size_t IDX_BYTES  = (size_t)B * N * 2;
    const size_t HIST_BYTES = (size_t)B * 4 * 256 * 4; // 2,097,152
    const size_t WS_A = PAIR_BYTES + HIST_BYTES;
    const size_t WS_B = KEY_BYTES + IDX_BYTES + HIST_BYTES;

    dim3 g(B), b(BLK);
    if (ws_size >= WS_A) {
        // Tier A: pipelined packed-u64 wave-private path.
        uint8_t* ws = (uint8_t*)d_ws;
        unsigned long long* pairWS  = (unsigned long long*)ws;
        uint32_t*           histWS  = (uint32_t*)(ws + PAIR_BYTES);
        unsigned long long* pairOUT = (unsigned long long*)d_out;  // 206MB in d_out

        hist4_fast<<<g, b, 0, stream>>>(wts, histWS);
        scatter_pl<0,  true,  false><<<g, b, 0, stream>>>(wts, nullptr, pairWS, nullptr, nullptr, histWS);
        scatter_pl<8,  false, false><<<g, b, 0, stream>>>(nullptr, pairWS, pairOUT, nullptr, nullptr, histWS);
        scatter_pl<16, false, false><<<g, b, 0, stream>>>(nullptr, pairOUT, pairWS, nullptr, nullptr, histWS);
        scatter_pl<24, false, true ><<<g, b, 0, stream>>>(nullptr, pairWS, nullptr, (uint32_t*)out0, out1, histWS);
        finalize_row<<<g, b, 0, stream>>>(out0, out1, out2);
    } else if (ws_size >= WS_B) {
        // Tier B: round-3 proven path (+ fast hist & merged finalize).
        uint8_t* ws = (uint8_t*)d_ws;
        uint32_t* keyWS  = (uint32_t*)ws;
        uint16_t* idxWS  = (uint16_t*)(ws + KEY_BYTES);
        uint32_t* histWS = (uint32_t*)(ws + KEY_BYTES + IDX_BYTES);
        uint32_t* keyOUT = (uint32_t*)out0;
        uint16_t* idxOUT = (uint16_t*)out1;

        hist4_fast<<<g, b, 0, stream>>>(wts, histWS);
        scatter_tile<0,  true,  false><<<g, b, 0, stream>>>(wts, nullptr, nullptr, keyWS, idxWS, nullptr, nullptr, histWS);
        scatter_tile<8,  false, false><<<g, b, 0, stream>>>(wts, keyWS, idxWS, keyOUT, idxOUT, nullptr, nullptr, histWS);
        scatter_tile<16, false, false><<<g, b, 0, stream>>>(wts, keyOUT, idxOUT, keyWS, idxWS, nullptr, nullptr, histWS);
        scatter_tile<24, false, true ><<<g, b, 0, stream>>>(wts, keyWS, idxWS, nullptr, nullptr, (uint32_t*)out0, out1, histWS);
        finalize_row<<<g, b, 0, stream>>>(out0, out1, out2);
    } else {
        // Tier C: no-workspace fallback.
        uint32_t* bufA = (uint32_t*)out0;
        uint32_t* bufB = (uint32_t*)out1;
        radix_pass_fb<0 ><<<g, b, 0, stream>>>(wts, nullptr, bufA);
        radix_pass_fb<8 ><<<g, b, 0, stream>>>(wts, bufA, bufB);
        radix_pass_fb<16><<<g, b, 0, stream>>>(wts, bufB, bufA);
        radix_pass_fb<24><<<g, b, 0, stream>>>(wts, bufA, bufB);
        finalize_fb<<<g, b, 0, stream>>>(wts, bufB, out0, out1, out2);
    }
}